// Round 16
// baseline (394.184 us; speedup 1.0000x reference)
//
#include <hip/hip_runtime.h>
#include <hip/hip_bf16.h>
#include <stdint.h>

#define B_  32
#define L_  256
#define T_  32
#define D_  300
#define H_  256
#define G3  768   // 3*H

__device__ __forceinline__ int sdot4(uint32_t a, uint32_t b, int acc) {
#if defined(__has_builtin) && __has_builtin(__builtin_amdgcn_sdot4)
  return __builtin_amdgcn_sdot4((int)a, (int)b, acc, false);
#else
  const int a0 = (int)(signed char)(a & 0xff),  b0 = (int)(signed char)(b & 0xff);
  const int a1 = (int)(signed char)((a >> 8) & 0xff),  b1 = (int)(signed char)((b >> 8) & 0xff);
  const int a2 = (int)(signed char)((a >> 16) & 0xff), b2 = (int)(signed char)((b >> 16) & 0xff);
  const int a3 = (int)(signed char)(a >> 24),          b3 = (int)(signed char)(b >> 24);
  return acc + a0 * b0 + a1 * b1 + a2 * b2 + a3 * b3;
#endif
}

__device__ __forceinline__ float rcp_f(float x) { return __builtin_amdgcn_rcpf(x); }
__device__ __forceinline__ float sigmoid_f(float x) { return rcp_f(1.0f + __expf(-x)); }
__device__ __forceinline__ float tanh_f(float x) {
  float e2 = __expf(2.0f * x);
  return 1.0f - 2.0f * rcp_f(e2 + 1.0f);
}

// ---- device body: pack Whh row-chunk-major i8 (chunk c*768+row as uint4) ----
__device__ __forceinline__ void pack_body(int blk, const float* __restrict__ Whh,
                                          uint32_t* __restrict__ wQ,
                                          float* __restrict__ sw) {
  const int row = blk * 4 + (threadIdx.x >> 6);
  const int lane = threadIdx.x & 63;           // dword index 0..63
  const float* wr = Whh + (long)row * H_;
  float m = 0.0f;
#pragma unroll
  for (int u = 0; u < 4; ++u) m = fmaxf(m, fabsf(wr[lane + 64 * u]));
  for (int off = 32; off > 0; off >>= 1) m = fmaxf(m, __shfl_xor(m, off, 64));
  const float inv = m > 0.0f ? 127.0f / m : 0.0f;
  if (lane == 0) sw[row] = m > 0.0f ? m / (127.0f * 127.0f) : 0.0f;
  uint32_t d = 0;
#pragma unroll
  for (int u = 0; u < 4; ++u) {
    int qv = __float2int_rn(wr[4 * lane + u] * inv);
    qv = qv > 127 ? 127 : (qv < -127 ? -127 : qv);
    d |= ((uint32_t)(qv & 0xff)) << (8 * u);
  }
  wQ[(((size_t)(lane >> 2) * G3 + row) << 2) + (lane & 3)] = d;
}

// ---- device body: per-row symmetric i8 quantizer ----
// rowidx: direct gather. Xin2/Xidx2: decoder-token gather (inline dtok).
__device__ __forceinline__ void quant_body(int blk, const float* __restrict__ A,
                                           const int* __restrict__ rowidx,
                                           const int* __restrict__ Xin2,
                                           const int* __restrict__ Xidx2,
                                           uint32_t* __restrict__ out,
                                           float* __restrict__ scale,
                                           int M, int K, int Kd) {
  const int row = blk * 4 + (threadIdx.x >> 6);
  const int lane = threadIdx.x & 63;
  if (row >= M) return;
  long src = row;
  if (rowidx) src = rowidx[row];
  else if (Xin2) src = Xin2[(row >> 5) * L_ + Xidx2[row]];
  const float* ar = A + src * (long)K;
  float m = 0.0f;
  for (int e = lane; e < K; e += 64) m = fmaxf(m, fabsf(ar[e]));
  for (int off = 32; off > 0; off >>= 1) m = fmaxf(m, __shfl_xor(m, off, 64));
  const float inv = m > 0.0f ? 127.0f / m : 0.0f;
  if (lane == 0) scale[row] = m * (1.0f / 127.0f);
  for (int kd = lane; kd < Kd; kd += 64) {
    uint32_t d = 0;
#pragma unroll
    for (int u = 0; u < 4; ++u) {
      const int e = 4 * kd + u;
      int qv = (e < K) ? __float2int_rn(ar[e] * inv) : 0;
      qv = qv > 127 ? 127 : (qv < -127 ? -127 : qv);
      d |= ((uint32_t)(qv & 0xff)) << (8 * u);
    }
    out[(long)row * Kd + kd] = d;
  }
}

// ---- one fused prep kernel: packs, weight/emb quants, bias sums ----
__global__ __launch_bounds__(256)
void prep_all(const float* __restrict__ Whh_e, const float* __restrict__ Whh_d,
              uint32_t* __restrict__ wQ_e, uint32_t* __restrict__ wQ_d,
              float* __restrict__ sw_e, float* __restrict__ sw_d,
              const float* __restrict__ Wih_e, const float* __restrict__ Wih_d,
              uint32_t* __restrict__ WihQ_e, uint32_t* __restrict__ WihQ_d,
              float* __restrict__ sWih_e, float* __restrict__ sWih_d,
              const float* __restrict__ W1, const float* __restrict__ W2,
              uint32_t* __restrict__ W1q, uint32_t* __restrict__ W2q,
              float* __restrict__ sW1, float* __restrict__ sW2,
              const float* __restrict__ emb, const int* __restrict__ Xin,
              const int* __restrict__ Xindex,
              uint32_t* __restrict__ Aqe, float* __restrict__ saAe,
              uint32_t* __restrict__ Aqd, float* __restrict__ saAd,
              const float* __restrict__ bih_e, const float* __restrict__ bhh_e,
              float* __restrict__ bsum_e,
              const float* __restrict__ bih_d, const float* __restrict__ bhh_d,
              float* __restrict__ bsum_d) {
  const int blk = blockIdx.x;
  if (blk < 192)        pack_body(blk, Whh_e, wQ_e, sw_e);
  else if (blk < 384)   pack_body(blk - 192, Whh_d, wQ_d, sw_d);
  else if (blk < 576)   quant_body(blk - 384, Wih_e, nullptr, nullptr, nullptr,
                                   WihQ_e, sWih_e, 768, 300, 80);
  else if (blk < 768)   quant_body(blk - 576, Wih_d, nullptr, nullptr, nullptr,
                                   WihQ_d, sWih_d, 768, 300, 80);
  else if (blk < 832)   quant_body(blk - 768, W1, nullptr, nullptr, nullptr,
                                   W1q, sW1, 256, 256, 64);
  else if (blk < 896)   quant_body(blk - 832, W2, nullptr, nullptr, nullptr,
                                   W2q, sW2, 256, 256, 64);
  else if (blk < 2944)  quant_body(blk - 896, emb, Xin, nullptr, nullptr,
                                   Aqe, saAe, 8192, 300, 80);
  else if (blk < 3200)  quant_body(blk - 2944, emb, nullptr, Xin, Xindex,
                                   Aqd, saAd, 1024, 300, 80);
  else {
    const int blk2 = blk - 3200;              // 0..5
    const int i = (blk2 % 3) * 256 + threadIdx.x;
    const float* bih = blk2 < 3 ? bih_e : bih_d;
    const float* bhh = blk2 < 3 ? bhh_e : bhh_d;
    float* bsum = blk2 < 3 ? bsum_e : bsum_d;
    float v = bih[i];
    if (i < 2 * H_) v += bhh[i];
    bsum[i] = v;
  }
}

// ---- fused post-GRU quantization (hn + doutb) ----
__global__ __launch_bounds__(256)
void post_quant(const float* __restrict__ hn, uint32_t* __restrict__ hnq,
                float* __restrict__ sahn,
                const float* __restrict__ doutb, uint32_t* __restrict__ dq,
                float* __restrict__ sad) {
  const int blk = blockIdx.x;
  if (blk < 2048) quant_body(blk, hn, nullptr, nullptr, nullptr, hnq, sahn, 8192, 256, 64);
  else            quant_body(blk - 2048, doutb, nullptr, nullptr, nullptr, dq, sad, 1024, 256, 64);
}

// ---- i8 GEMM: C[M,N] = (Aq . Wq^T) * sa[m] * sw[n] (+bias[n]) ----
template<bool TRANSP, bool BIAS>
__global__ __launch_bounds__(256)
void gemm_i8(const uint32_t* __restrict__ Aq, const float* __restrict__ sa,
             const uint32_t* __restrict__ Wq, const float* __restrict__ swc,
             const float* __restrict__ bias, float* __restrict__ C,
             int M, int N, int Kd) {
  __shared__ uint32_t As[8][68];
  __shared__ uint32_t Ws[8][68];
  const int tid = threadIdx.x;
  const int bm = blockIdx.x, bn = blockIdx.y;
  const int ty = tid >> 4, tx = tid & 15;
  const int srow = tid >> 2;
  const int skd = (tid & 3) << 1;
  const uint32_t* Arow = Aq + (long)(bm * 64 + srow) * Kd + skd;
  const uint32_t* Wrow = Wq + (long)(bn * 64 + srow) * Kd + skd;
  int acc[4][4] = {};
  for (int k0 = 0; k0 < Kd; k0 += 8) {
    const uint32_t a0 = Arow[k0], a1 = Arow[k0 + 1];
    const uint32_t w0 = Wrow[k0], w1 = Wrow[k0 + 1];
    __syncthreads();
    As[skd][srow] = a0; As[skd + 1][srow] = a1;
    Ws[skd][srow] = w0; Ws[skd + 1][srow] = w1;
    __syncthreads();
#pragma unroll
    for (int kd = 0; kd < 8; ++kd) {
      const uint4 a4 = *(const uint4*)&As[kd][ty << 2];
      const uint4 b4 = *(const uint4*)&Ws[kd][tx << 2];
      acc[0][0] = sdot4(a4.x, b4.x, acc[0][0]);
      acc[0][1] = sdot4(a4.x, b4.y, acc[0][1]);
      acc[0][2] = sdot4(a4.x, b4.z, acc[0][2]);
      acc[0][3] = sdot4(a4.x, b4.w, acc[0][3]);
      acc[1][0] = sdot4(a4.y, b4.x, acc[1][0]);
      acc[1][1] = sdot4(a4.y, b4.y, acc[1][1]);
      acc[1][2] = sdot4(a4.y, b4.z, acc[1][2]);
      acc[1][3] = sdot4(a4.y, b4.w, acc[1][3]);
      acc[2][0] = sdot4(a4.z, b4.x, acc[2][0]);
      acc[2][1] = sdot4(a4.z, b4.y, acc[2][1]);
      acc[2][2] = sdot4(a4.z, b4.z, acc[2][2]);
      acc[2][3] = sdot4(a4.z, b4.w, acc[2][3]);
      acc[3][0] = sdot4(a4.w, b4.x, acc[3][0]);
      acc[3][1] = sdot4(a4.w, b4.y, acc[3][1]);
      acc[3][2] = sdot4(a4.w, b4.z, acc[3][2]);
      acc[3][3] = sdot4(a4.w, b4.w, acc[3][3]);
    }
  }
#pragma unroll
  for (int i = 0; i < 4; ++i) {
    const int m = bm * 64 + (ty << 2) + i;
    const float sai = sa[m];
#pragma unroll
    for (int j = 0; j < 4; ++j) {
      const int n = bn * 64 + (tx << 2) + j;
      float v = (float)acc[i][j] * sai * swc[n];
      if (BIAS) v += bias[n];
      if (TRANSP) C[(((long)(m >> 8) * N + n) << 8) + (m & 255)] = v;
      else        C[(long)m * N + n] = v;
    }
  }
}

// ==== sequential GRU: 1024 thr, 4-way K-split, 8 reg + 4 streamed chunks,
// h distributed via per-lane ds_read + v_readlane -> SGPRs (dot4 scalar src).
// r14 lesson: per-gate 2-load rounds exposed L2 latency 3x/step and broadcast
// b128 h-reads cost 770 cy of LDS pipe. Now: 1 LDS op/wave for h (16 total),
// all 4 streamed loads issued at step top (one latency exposure), partials
// exchanged as one int4 b128 (24 ops vs 72 b32).
// NOTE: macro params must NOT be named like vector members (r15: `w` param
// made `w.w` expand to `sn1.sn1`).

#define PIN4(v) asm volatile("" : "+v"(v.x), "+v"(v.y), "+v"(v.z), "+v"(v.w))
#define DOTS(acc, wv_, ha, hb, hc, hd) { \
  acc = sdot4(wv_.x, ha, acc); acc = sdot4(wv_.y, hb, acc); \
  acc = sdot4(wv_.z, hc, acc); acc = sdot4(wv_.w, hd, acc); }

__global__ __launch_bounds__(1024)
void gru_seq(const float* __restrict__ xg, const uint4* __restrict__ wQv,
             const float* __restrict__ sw, const float* __restrict__ bhh,
             const float* __restrict__ h0, float* __restrict__ hout,
             float* __restrict__ hlast, int S) {
  const int b = blockIdx.x;
  const int tid = threadIdx.x;
  const int j = tid & 255;
  const int q = tid >> 8;
  const int qb = q << 4;                      // readlane base (slice dword 0)
  const int c0 = q * 4;
  const int o_r0 = (c0 + 0) * G3 + j;
  const int o_z0 = o_r0 + H_;
  const int o_n0 = o_r0 + 2 * H_;
  const int o_n1 = (c0 + 1) * G3 + 2 * H_ + j;
  // 8 register-resident chunks: r/z keep u=1,2,3; n keeps u=2,3
  uint4 wr1 = wQv[(c0 + 1) * G3 + j];
  uint4 wr2 = wQv[(c0 + 2) * G3 + j];
  uint4 wr3 = wQv[(c0 + 3) * G3 + j];
  uint4 wz1 = wQv[(c0 + 1) * G3 + H_ + j];
  uint4 wz2 = wQv[(c0 + 2) * G3 + H_ + j];
  uint4 wz3 = wQv[(c0 + 3) * G3 + H_ + j];
  uint4 wn2 = wQv[(c0 + 2) * G3 + 2 * H_ + j];
  uint4 wn3 = wQv[(c0 + 3) * G3 + 2 * H_ + j];
  PIN4(wr1); PIN4(wr2); PIN4(wr3);
  PIN4(wz1); PIN4(wz2); PIN4(wz3);
  PIN4(wn2); PIN4(wn3);
  __shared__ uint32_t h2[2][64];              // i8 h, double-buffered (256 B each)
  __shared__ int4 partv[4][H_];               // [q][j]; q=0 unused
  float bhn = 0.0f, h = 0.0f, swr = 0.0f, swz = 0.0f, swn = 0.0f;
  const float* xp = xg + (long)b * S * G3;
  float* hp_out = hout + (long)b * S * H_;
  if (q == 0) {
    bhn = bhh[2 * H_ + j];
    swr = sw[j]; swz = sw[H_ + j]; swn = sw[2 * H_ + j];
    h = h0 ? h0[b * H_ + j] : 0.0f;
    ((signed char*)h2[0])[j] = (signed char)__float2int_rn(h * 127.0f);
  }
  __syncthreads();
  for (int t = 0; t < S; ++t) {
    // whole h into the wave, one per-lane dword
    const uint32_t hv = h2[t & 1][tid & 63];
    // all streamed chunks issued up front (single latency exposure)
    const uint4 sr  = wQv[o_r0];
    const uint4 szc = wQv[o_z0];
    const uint4 sn0 = wQv[o_n0];
    const uint4 sn1 = wQv[o_n1];
    float xr = 0.0f, xz = 0.0f, xn = 0.0f;
    if (q == 0) { xr = xp[j]; xz = xp[H_ + j]; xn = xp[2 * H_ + j]; }
    // wave-uniform slice -> SGPRs
    const uint32_t hs0  = __builtin_amdgcn_readlane(hv, qb + 0);
    const uint32_t hs1  = __builtin_amdgcn_readlane(hv, qb + 1);
    const uint32_t hs2  = __builtin_amdgcn_readlane(hv, qb + 2);
    const uint32_t hs3  = __builtin_amdgcn_readlane(hv, qb + 3);
    const uint32_t hs4  = __builtin_amdgcn_readlane(hv, qb + 4);
    const uint32_t hs5  = __builtin_amdgcn_readlane(hv, qb + 5);
    const uint32_t hs6  = __builtin_amdgcn_readlane(hv, qb + 6);
    const uint32_t hs7  = __builtin_amdgcn_readlane(hv, qb + 7);
    const uint32_t hs8  = __builtin_amdgcn_readlane(hv, qb + 8);
    const uint32_t hs9  = __builtin_amdgcn_readlane(hv, qb + 9);
    const uint32_t hs10 = __builtin_amdgcn_readlane(hv, qb + 10);
    const uint32_t hs11 = __builtin_amdgcn_readlane(hv, qb + 11);
    const uint32_t hs12 = __builtin_amdgcn_readlane(hv, qb + 12);
    const uint32_t hs13 = __builtin_amdgcn_readlane(hv, qb + 13);
    const uint32_t hs14 = __builtin_amdgcn_readlane(hv, qb + 14);
    const uint32_t hs15 = __builtin_amdgcn_readlane(hv, qb + 15);
    int ar = 0, az = 0, an = 0;
    // register chunks first (no vmem dependency)
    DOTS(ar, wr1, hs4, hs5, hs6, hs7)
    DOTS(ar, wr2, hs8, hs9, hs10, hs11)
    DOTS(ar, wr3, hs12, hs13, hs14, hs15)
    DOTS(az, wz1, hs4, hs5, hs6, hs7)
    DOTS(az, wz2, hs8, hs9, hs10, hs11)
    DOTS(az, wz3, hs12, hs13, hs14, hs15)
    DOTS(an, wn2, hs8, hs9, hs10, hs11)
    DOTS(an, wn3, hs12, hs13, hs14, hs15)
    // streamed chunks (loads have had the whole reg-dot block to land)
    DOTS(ar, sr,  hs0, hs1, hs2, hs3)
    DOTS(az, szc, hs0, hs1, hs2, hs3)
    DOTS(an, sn0, hs0, hs1, hs2, hs3)
    DOTS(an, sn1, hs4, hs5, hs6, hs7)
    if (q) partv[q][j] = make_int4(ar, az, an, 0);
    __syncthreads();
    if (q == 0) {
      const int4 p1 = partv[1][j];
      const int4 p2 = partv[2][j];
      const int4 p3 = partv[3][j];
      const float arf = (float)(ar + p1.x + p2.x + p3.x) * swr;
      const float azf = (float)(az + p1.y + p2.y + p3.y) * swz;
      const float anf = (float)(an + p1.z + p2.z + p3.z) * swn;
      const float r = sigmoid_f(xr + arf);           // xr has bih_r + bhh_r
      const float z = sigmoid_f(xz + azf);           // xz has bih_z + bhh_z
      const float n = tanh_f(xn + r * (anf + bhn));
      h = (1.0f - z) * n + z * h;
      hp_out[j] = h;
      ((signed char*)h2[(t & 1) ^ 1])[j] = (signed char)__float2int_rn(h * 127.0f);
    }
    xp += G3;
    hp_out += H_;
    __syncthreads();
  }
  if (q == 0 && hlast) hlast[b * H_ + j] = h;
}

// ---- fused pointer layer + masked log-softmax + loss accumulation ----
__global__ __launch_bounds__(256)
void pointer_loss(const float* __restrict__ WEt, const float* __restrict__ WD,
                  const float* __restrict__ Vv,
                  const int* __restrict__ Xindex, const int* __restrict__ Yindex,
                  const int* __restrict__ lens, float* __restrict__ out) {
  const int t = blockIdx.x, b = blockIdx.y;
  const int l = threadIdx.x;
  __shared__ float wd_s[H_], vv_s[H_];
  __shared__ float rbuf[4], sbuf[4], vy_s;
  const int bt = b * T_ + t;
  wd_s[l] = WD[(long)bt * H_ + l];
  vv_s[l] = Vv[l] * 1.0507009873554805f;
  __syncthreads();
  const float* wet = WEt + (long)b * H_ * L_;
  const float alpha = 1.6732632423543772f;
  float acc = 0.0f;
#pragma unroll 4
  for (int hh = 0; hh < H_; ++hh) {
    const float xsum = wet[hh * L_ + l] + wd_s[hh];
    const float sneg = alpha * (__expf(xsum) - 1.0f);
    const float s = xsum > 0.0f ? xsum : sneg;
    acc = fmaf(s, vv_s[hh], acc);
  }
  float v;
  {
    const float sneg = alpha * (__expf(acc) - 1.0f);
    v = 1.0507009873554805f * (acc > 0.0f ? acc : sneg);
  }
  const int start = Xindex[bt];
  const int len = lens[b];
  const bool valid = (l >= start) && (l < len);
  const int y = Yindex[bt];
  if (l == y) vy_s = v;
  float m = valid ? v : -INFINITY;
  for (int off = 32; off > 0; off >>= 1) m = fmaxf(m, __shfl_xor(m, off, 64));
  const int wid = l >> 6, lane = l & 63;
  if (lane == 0) rbuf[wid] = m;
  __syncthreads();
  const float mx = fmaxf(fmaxf(rbuf[0], rbuf[1]), fmaxf(rbuf[2], rbuf[3]));
  float e = valid ? __expf(v - mx) : 0.0f;
  for (int off = 32; off > 0; off >>= 1) e += __shfl_xor(e, off, 64);
  if (lane == 0) sbuf[wid] = e;
  __syncthreads();
  if (l == 0) {
    const float sum = sbuf[0] + sbuf[1] + sbuf[2] + sbuf[3];
    atomicAdd(out, (mx + __logf(sum) - vy_s) * (1.0f / (B_ * T_)));
  }
}

extern "C" void kernel_launch(void* const* d_in, const int* in_sizes, int n_in,
                              void* d_out, int out_size, void* d_ws, size_t ws_size,
                              hipStream_t stream) {
  (void)in_sizes; (void)n_in; (void)out_size; (void)ws_size;
  const int*   Xin    = (const int*)d_in[0];
  const int*   Xindex = (const int*)d_in[1];
  const int*   Yindex = (const int*)d_in[2];
  const int*   lens   = (const int*)d_in[3];
  const float* emb    = (const float*)d_in[4];
  const float* Wih_e  = (const float*)d_in[5];
  const float* Whh_e  = (const float*)d_in[6];
  const float* bih_e  = (const float*)d_in[7];
  const float* bhh_e  = (const float*)d_in[8];
  const float* Wih_d  = (const float*)d_in[9];
  const float* Whh_d  = (const float*)d_in[10];
  const float* bih_d  = (const float*)d_in[11];
  const float* bhh_d  = (const float*)d_in[12];
  const float* W1     = (const float*)d_in[13];
  const float* W2     = (const float*)d_in[14];
  const float* Vv     = (const float*)d_in[15];

  char* p = (char*)d_ws;
  auto take = [&](size_t bytes) { void* q = (void*)p; p += (bytes + 255) & ~(size_t)255; return q; };
  uint32_t* wQ_e   = (uint32_t*)take((size_t)64 * G3 * 4);
  uint32_t* wQ_d   = (uint32_t*)take((size_t)64 * G3 * 4);
  float*    sw_e   = (float*)take((size_t)768 * 4);
  float*    sw_d   = (float*)take((size_t)768 * 4);
  uint32_t* WihQ_e = (uint32_t*)take((size_t)768 * 80 * 4);
  uint32_t* WihQ_d = (uint32_t*)take((size_t)768 * 80 * 4);
  float*    sWih_e = (float*)take((size_t)768 * 4);
  float*    sWih_d = (float*)take((size_t)768 * 4);
  uint32_t* W1q    = (uint32_t*)take((size_t)256 * 64 * 4);
  uint32_t* W2q    = (uint32_t*)take((size_t)256 * 64 * 4);
  float*    sW1    = (float*)take((size_t)256 * 4);
  float*    sW2    = (float*)take((size_t)256 * 4);
  float*    bsum_e = (float*)take((size_t)768 * 4);
  float*    bsum_d = (float*)take((size_t)768 * 4);
  float*    xg_e   = (float*)take((size_t)8192 * 768 * 4);   // reused as WEt later
  float*    xg_d   = (float*)take((size_t)1024 * 768 * 4);
  float*    hn     = (float*)take((size_t)8192 * 256 * 4);
  float*    hend   = (float*)take((size_t)8192 * 4);
  float*    hl_d   = (float*)take((size_t)8192 * 4);
  float*    doutb  = (float*)take((size_t)1024 * 256 * 4);
  float*    WDb    = (float*)take((size_t)1024 * 256 * 4);
  uint32_t* Aqe    = (uint32_t*)take((size_t)8192 * 80 * 4); // reused as hnq later
  float*    saAe   = (float*)take((size_t)8192 * 4);         // reused as sahn
  uint32_t* Aqd    = (uint32_t*)take((size_t)1024 * 80 * 4); // reused as dq
  float*    saAd   = (float*)take((size_t)1024 * 4);         // reused as sad
  float*    WEt  = xg_e;            // xg_e dead after encoder GRU
  uint32_t* hnq  = Aqe;             // Aqe dead after xg GEMMs
  float*    sahn = saAe;
  uint32_t* dq   = Aqd;
  float*    sad  = saAd;

  hipMemsetAsync(d_out, 0, sizeof(float), stream);

  // single fused prep: packs + weight quants + emb quants + bias sums
  hipLaunchKernelGGL(prep_all, dim3(3206), dim3(256), 0, stream,
                     Whh_e, Whh_d, wQ_e, wQ_d, sw_e, sw_d,
                     Wih_e, Wih_d, WihQ_e, WihQ_d, sWih_e, sWih_d,
                     W1, W2, W1q, W2q, sW1, sW2,
                     emb, Xin, Xindex, Aqe, saAe, Aqd, saAd,
                     bih_e, bhh_e, bsum_e, bih_d, bhh_d, bsum_d);

  // xg = Aq @ WihQ^T scaled + bsum
  hipLaunchKernelGGL((gemm_i8<false, true>), dim3(128, 12), dim3(256), 0, stream,
                     Aqe, saAe, WihQ_e, sWih_e, bsum_e, xg_e, 8192, 768, 80);
  hipLaunchKernelGGL((gemm_i8<false, true>), dim3(16, 12), dim3(256), 0, stream,
                     Aqd, saAd, WihQ_d, sWih_d, bsum_d, xg_d, 1024, 768, 80);

  // encoder GRU (h0 = 0) -> hn, hend; decoder GRU (h0 = hend) -> doutb
  hipLaunchKernelGGL(gru_seq, dim3(32), dim3(1024), 0, stream,
                     xg_e, (const uint4*)wQ_e, sw_e, bhh_e, (const float*)nullptr,
                     hn, hend, L_);
  hipLaunchKernelGGL(gru_seq, dim3(32), dim3(1024), 0, stream,
                     xg_d, (const uint4*)wQ_d, sw_d, bhh_d, hend, doutb, hl_d, T_);

  // fused output quantization (hn + doutb)
  hipLaunchKernelGGL(post_quant, dim3(2304), dim3(256), 0, stream,
                     hn, hnq, sahn, doutb, dq, sad);

  // pointer GEMMs: WEt[b][k][l] (transposed store), WD[b,t,k]
  hipLaunchKernelGGL((gemm_i8<true, false>), dim3(128, 4), dim3(256), 0, stream,
                     hnq, sahn, W1q, sW1, (const float*)nullptr, WEt, 8192, 256, 64);
  hipLaunchKernelGGL((gemm_i8<false, false>), dim3(16, 4), dim3(256), 0, stream,
                     dq, sad, W2q, sW2, (const float*)nullptr, WDb, 1024, 256, 64);

  // fused pointer layer + loss
  hipLaunchKernelGGL(pointer_loss, dim3(T_, B_), dim3(256), 0, stream,
                     WEt, WDb, Vv, Xindex, Yindex, lens, (float*)d_out);
}

// Round 17
// 301.260 us; speedup vs baseline: 1.3085x; 1.3085x over previous
//
#include <hip/hip_runtime.h>
#include <hip/hip_bf16.h>
#include <stdint.h>

#define B_  32
#define L_  256
#define T_  32
#define D_  300
#define H_  256
#define G3  768   // 3*H

__device__ __forceinline__ int sdot4(uint32_t a, uint32_t b, int acc) {
#if defined(__has_builtin) && __has_builtin(__builtin_amdgcn_sdot4)
  return __builtin_amdgcn_sdot4((int)a, (int)b, acc, false);
#else
  const int a0 = (int)(signed char)(a & 0xff),  b0 = (int)(signed char)(b & 0xff);
  const int a1 = (int)(signed char)((a >> 8) & 0xff),  b1 = (int)(signed char)((b >> 8) & 0xff);
  const int a2 = (int)(signed char)((a >> 16) & 0xff), b2 = (int)(signed char)((b >> 16) & 0xff);
  const int a3 = (int)(signed char)(a >> 24),          b3 = (int)(signed char)(b >> 24);
  return acc + a0 * b0 + a1 * b1 + a2 * b2 + a3 * b3;
#endif
}

__device__ __forceinline__ float rcp_f(float x) { return __builtin_amdgcn_rcpf(x); }
__device__ __forceinline__ float sigmoid_f(float x) { return rcp_f(1.0f + __expf(-x)); }
__device__ __forceinline__ float tanh_f(float x) {
  float e2 = __expf(2.0f * x);
  return 1.0f - 2.0f * rcp_f(e2 + 1.0f);
}

// ---- pack Whh [768][256] f32 -> wQv uint4[16 chunks][768 rows] + sw[768] ----
__device__ __forceinline__ void pack_body(int blk, const float* __restrict__ Whh,
                                          uint32_t* __restrict__ wQ,
                                          float* __restrict__ sw) {
  const int row = blk * 4 + (threadIdx.x >> 6);
  const int lane = threadIdx.x & 63;           // k-dword index 0..63
  const float* wr = Whh + (long)row * H_;
  float m = 0.0f;
#pragma unroll
  for (int u = 0; u < 4; ++u) m = fmaxf(m, fabsf(wr[lane + 64 * u]));
  for (int off = 32; off > 0; off >>= 1) m = fmaxf(m, __shfl_xor(m, off, 64));
  const float inv = m > 0.0f ? 127.0f / m : 0.0f;
  if (lane == 0) sw[row] = m > 0.0f ? m / (127.0f * 127.0f) : 0.0f;
  uint32_t d = 0;
#pragma unroll
  for (int u = 0; u < 4; ++u) {
    int qv = __float2int_rn(wr[4 * lane + u] * inv);
    qv = qv > 127 ? 127 : (qv < -127 ? -127 : qv);
    d |= ((uint32_t)(qv & 0xff)) << (8 * u);
  }
  wQ[(((size_t)(lane >> 2) * G3 + row) << 2) + (lane & 3)] = d;
}

// ---- per-row symmetric i8 quantizer, 4 rows/block (256 threads) ----
__device__ __forceinline__ void quant_body(int blk, const float* __restrict__ A,
                                           const int* __restrict__ rowidx,
                                           const int* __restrict__ Xin2,
                                           const int* __restrict__ Xidx2,
                                           uint32_t* __restrict__ out,
                                           float* __restrict__ scale,
                                           int M, int K, int Kd) {
  const int row = blk * 4 + (threadIdx.x >> 6);
  const int lane = threadIdx.x & 63;
  if (row >= M) return;
  long src = row;
  if (rowidx) src = rowidx[row];
  else if (Xin2) src = Xin2[(row >> 5) * L_ + Xidx2[row]];
  const float* ar = A + src * (long)K;
  float m = 0.0f;
  for (int e = lane; e < K; e += 64) m = fmaxf(m, fabsf(ar[e]));
  for (int off = 32; off > 0; off >>= 1) m = fmaxf(m, __shfl_xor(m, off, 64));
  const float inv = m > 0.0f ? 127.0f / m : 0.0f;
  if (lane == 0) scale[row] = m * (1.0f / 127.0f);
  for (int kd = lane; kd < Kd; kd += 64) {
    uint32_t d = 0;
#pragma unroll
    for (int u = 0; u < 4; ++u) {
      const int e = 4 * kd + u;
      int qv = (e < K) ? __float2int_rn(ar[e] * inv) : 0;
      qv = qv > 127 ? 127 : (qv < -127 ? -127 : qv);
      d |= ((uint32_t)(qv & 0xff)) << (8 * u);
    }
    out[(long)row * Kd + kd] = d;
  }
}

// ---- 16 rows/block variant (1024 threads) ----
__device__ __forceinline__ void quant16(int blk, const float* __restrict__ A,
                                        uint32_t* __restrict__ out,
                                        float* __restrict__ scale,
                                        int M, int K, int Kd) {
  const int row = blk * 16 + (threadIdx.x >> 6);
  const int lane = threadIdx.x & 63;
  if (row >= M) return;
  const float* ar = A + (long)row * K;
  float m = 0.0f;
  for (int e = lane; e < K; e += 64) m = fmaxf(m, fabsf(ar[e]));
  for (int off = 32; off > 0; off >>= 1) m = fmaxf(m, __shfl_xor(m, off, 64));
  const float inv = m > 0.0f ? 127.0f / m : 0.0f;
  if (lane == 0) scale[row] = m * (1.0f / 127.0f);
  for (int kd = lane; kd < Kd; kd += 64) {
    uint32_t d = 0;
#pragma unroll
    for (int u = 0; u < 4; ++u) {
      const int e = 4 * kd + u;
      int qv = (e < K) ? __float2int_rn(ar[e] * inv) : 0;
      qv = qv > 127 ? 127 : (qv < -127 ? -127 : qv);
      d |= ((uint32_t)(qv & 0xff)) << (8 * u);
    }
    out[(long)row * Kd + kd] = d;
  }
}

// ---- one fused prep kernel: packs, weight/emb quants, bias sums ----
__global__ __launch_bounds__(256)
void prep_all(const float* __restrict__ Whh_e, const float* __restrict__ Whh_d,
              uint32_t* __restrict__ wQ_e, uint32_t* __restrict__ wQ_d,
              float* __restrict__ sw_e, float* __restrict__ sw_d,
              const float* __restrict__ Wih_e, const float* __restrict__ Wih_d,
              uint32_t* __restrict__ WihQ_e, uint32_t* __restrict__ WihQ_d,
              float* __restrict__ sWih_e, float* __restrict__ sWih_d,
              const float* __restrict__ W1, const float* __restrict__ W2,
              uint32_t* __restrict__ W1q, uint32_t* __restrict__ W2q,
              float* __restrict__ sW1, float* __restrict__ sW2,
              const float* __restrict__ emb, const int* __restrict__ Xin,
              const int* __restrict__ Xindex,
              uint32_t* __restrict__ Aqe, float* __restrict__ saAe,
              uint32_t* __restrict__ Aqd, float* __restrict__ saAd,
              const float* __restrict__ bih_e, const float* __restrict__ bhh_e,
              float* __restrict__ bsum_e,
              const float* __restrict__ bih_d, const float* __restrict__ bhh_d,
              float* __restrict__ bsum_d) {
  const int blk = blockIdx.x;
  if (blk < 192)        pack_body(blk, Whh_e, wQ_e, sw_e);
  else if (blk < 384)   pack_body(blk - 192, Whh_d, wQ_d, sw_d);
  else if (blk < 576)   quant_body(blk - 384, Wih_e, nullptr, nullptr, nullptr,
                                   WihQ_e, sWih_e, 768, 300, 80);
  else if (blk < 768)   quant_body(blk - 576, Wih_d, nullptr, nullptr, nullptr,
                                   WihQ_d, sWih_d, 768, 300, 80);
  else if (blk < 832)   quant_body(blk - 768, W1, nullptr, nullptr, nullptr,
                                   W1q, sW1, 256, 256, 64);
  else if (blk < 896)   quant_body(blk - 832, W2, nullptr, nullptr, nullptr,
                                   W2q, sW2, 256, 256, 64);
  else if (blk < 2944)  quant_body(blk - 896, emb, Xin, nullptr, nullptr,
                                   Aqe, saAe, 8192, 300, 80);
  else if (blk < 3200)  quant_body(blk - 2944, emb, nullptr, Xin, Xindex,
                                   Aqd, saAd, 1024, 300, 80);
  else {
    const int blk2 = blk - 3200;              // 0..5
    const int i = (blk2 % 3) * 256 + threadIdx.x;
    const float* bih = blk2 < 3 ? bih_e : bih_d;
    const float* bhh = blk2 < 3 ? bhh_e : bhh_d;
    float* bsum = blk2 < 3 ? bsum_e : bsum_d;
    float v = bih[i];
    if (i < 2 * H_) v += bhh[i];
    bsum[i] = v;
  }
}

// ---- i8 GEMM body: C[M,N] = (Aq . Wq^T) * sa[m] * sw[n] (+bias[n]) ----
__device__ __forceinline__
void gemm_body(const uint32_t* __restrict__ Aq, const float* __restrict__ sa,
               const uint32_t* __restrict__ Wq, const float* __restrict__ swc,
               const float* __restrict__ bias, float* __restrict__ C,
               int bm, int bn, int M, int N, int Kd, bool transp, bool biasF) {
  __shared__ uint32_t As[8][68];
  __shared__ uint32_t Ws[8][68];
  const int tid = threadIdx.x;
  const int ty = tid >> 4, tx = tid & 15;
  const int srow = tid >> 2;
  const int skd = (tid & 3) << 1;
  const uint32_t* Arow = Aq + (long)(bm * 64 + srow) * Kd + skd;
  const uint32_t* Wrow = Wq + (long)(bn * 64 + srow) * Kd + skd;
  int acc[4][4] = {};
  for (int k0 = 0; k0 < Kd; k0 += 8) {
    const uint32_t a0 = Arow[k0], a1 = Arow[k0 + 1];
    const uint32_t w0 = Wrow[k0], w1 = Wrow[k0 + 1];
    __syncthreads();
    As[skd][srow] = a0; As[skd + 1][srow] = a1;
    Ws[skd][srow] = w0; Ws[skd + 1][srow] = w1;
    __syncthreads();
#pragma unroll
    for (int kd = 0; kd < 8; ++kd) {
      const uint4 a4 = *(const uint4*)&As[kd][ty << 2];
      const uint4 b4 = *(const uint4*)&Ws[kd][tx << 2];
      acc[0][0] = sdot4(a4.x, b4.x, acc[0][0]);
      acc[0][1] = sdot4(a4.x, b4.y, acc[0][1]);
      acc[0][2] = sdot4(a4.x, b4.z, acc[0][2]);
      acc[0][3] = sdot4(a4.x, b4.w, acc[0][3]);
      acc[1][0] = sdot4(a4.y, b4.x, acc[1][0]);
      acc[1][1] = sdot4(a4.y, b4.y, acc[1][1]);
      acc[1][2] = sdot4(a4.y, b4.z, acc[1][2]);
      acc[1][3] = sdot4(a4.y, b4.w, acc[1][3]);
      acc[2][0] = sdot4(a4.z, b4.x, acc[2][0]);
      acc[2][1] = sdot4(a4.z, b4.y, acc[2][1]);
      acc[2][2] = sdot4(a4.z, b4.z, acc[2][2]);
      acc[2][3] = sdot4(a4.z, b4.w, acc[2][3]);
      acc[3][0] = sdot4(a4.w, b4.x, acc[3][0]);
      acc[3][1] = sdot4(a4.w, b4.y, acc[3][1]);
      acc[3][2] = sdot4(a4.w, b4.z, acc[3][2]);
      acc[3][3] = sdot4(a4.w, b4.w, acc[3][3]);
    }
  }
#pragma unroll
  for (int i = 0; i < 4; ++i) {
    const int m = bm * 64 + (ty << 2) + i;
    const float sai = sa[m];
#pragma unroll
    for (int j = 0; j < 4; ++j) {
      const int n = bn * 64 + (tx << 2) + j;
      float v = (float)acc[i][j] * sai * swc[n];
      if (biasF) v += bias[n];
      if (transp) C[(((long)(m >> 8) * N + n) << 8) + (m & 255)] = v;
      else        C[(long)m * N + n] = v;
    }
  }
}

// ---- fused xg GEMMs (encoder + decoder inputs) ----
__global__ __launch_bounds__(256)
void xg_gemms(const uint32_t* __restrict__ Aqe, const float* __restrict__ saAe,
              const uint32_t* __restrict__ WihQ_e, const float* __restrict__ sWih_e,
              const float* __restrict__ bsum_e, float* __restrict__ xg_e,
              const uint32_t* __restrict__ Aqd, const float* __restrict__ saAd,
              const uint32_t* __restrict__ WihQ_d, const float* __restrict__ sWih_d,
              const float* __restrict__ bsum_d, float* __restrict__ xg_d) {
  const int blk = blockIdx.x;
  if (blk < 1536)
    gemm_body(Aqe, saAe, WihQ_e, sWih_e, bsum_e, xg_e,
              blk % 128, blk / 128, 8192, 768, 80, false, true);
  else {
    const int k = blk - 1536;
    gemm_body(Aqd, saAd, WihQ_d, sWih_d, bsum_d, xg_d,
              k % 16, k / 16, 1024, 768, 80, false, true);
  }
}

// ==== clean streaming GRU block: 1024 thr, 4-way K-split, 12 coalesced
// dwordx4 weight loads per thread per step (r8 used 48 scalar dwords ->
// 768 VMEM issues/CU/step; this cuts issue 4x). h i8 double-buffered in LDS
// (4 broadcast b128/thread), partials as one int4 b128. ====

#define DOTS(acc, wv_, hp_) { \
  acc = sdot4(wv_.x, hp_.x, acc); acc = sdot4(wv_.y, hp_.y, acc); \
  acc = sdot4(wv_.z, hp_.z, acc); acc = sdot4(wv_.w, hp_.w, acc); }

__device__ __forceinline__
void gru_block(int b, const float* __restrict__ xg, const uint4* __restrict__ wQv,
               const float* __restrict__ sw, const float* __restrict__ bhh,
               const float* __restrict__ h0, float* __restrict__ hout,
               float* __restrict__ hlast, int S,
               uint32_t (*h2)[64], int4 (*partv)[H_]) {
  const int tid = threadIdx.x;
  const int j = tid & 255;
  const int q = tid >> 8;
  const int base = (q * 4) * G3 + j;     // chunk (q*4+u), row j at base + u*G3
  float bhn = 0.0f, h = 0.0f, swr = 0.0f, swz = 0.0f, swn = 0.0f;
  const float* xp = xg + (long)b * S * G3;
  float* hp_out = hout + (long)b * S * H_;
  if (q == 0) {
    bhn = bhh[2 * H_ + j];
    swr = sw[j]; swz = sw[H_ + j]; swn = sw[2 * H_ + j];
    h = h0 ? h0[b * H_ + j] : 0.0f;
    ((signed char*)h2[0])[j] = (signed char)__float2int_rn(h * 127.0f);
  }
  __syncthreads();
  for (int t = 0; t < S; ++t) {
    const uint4* hq = (const uint4*)h2[t & 1] + q * 4;
    const uint4 hp0 = hq[0], hp1 = hq[1], hp2 = hq[2], hp3 = hq[3];
    float xr = 0.0f, xz = 0.0f, xn = 0.0f;
    if (q == 0) { xr = xp[j]; xz = xp[H_ + j]; xn = xp[2 * H_ + j]; }
    int ar = 0, az = 0, an = 0;
    {
      const uint4 a0 = wQv[base];
      const uint4 a1 = wQv[base + G3];
      const uint4 a2 = wQv[base + 2 * G3];
      const uint4 a3 = wQv[base + 3 * G3];
      DOTS(ar, a0, hp0) DOTS(ar, a1, hp1) DOTS(ar, a2, hp2) DOTS(ar, a3, hp3)
    }
    {
      const uint4 a0 = wQv[base + H_];
      const uint4 a1 = wQv[base + G3 + H_];
      const uint4 a2 = wQv[base + 2 * G3 + H_];
      const uint4 a3 = wQv[base + 3 * G3 + H_];
      DOTS(az, a0, hp0) DOTS(az, a1, hp1) DOTS(az, a2, hp2) DOTS(az, a3, hp3)
    }
    {
      const uint4 a0 = wQv[base + 2 * H_];
      const uint4 a1 = wQv[base + G3 + 2 * H_];
      const uint4 a2 = wQv[base + 2 * G3 + 2 * H_];
      const uint4 a3 = wQv[base + 3 * G3 + 2 * H_];
      DOTS(an, a0, hp0) DOTS(an, a1, hp1) DOTS(an, a2, hp2) DOTS(an, a3, hp3)
    }
    if (q) partv[q][j] = make_int4(ar, az, an, 0);
    __syncthreads();
    if (q == 0) {
      const int4 p1 = partv[1][j];
      const int4 p2 = partv[2][j];
      const int4 p3 = partv[3][j];
      const float arf = (float)(ar + p1.x + p2.x + p3.x) * swr;
      const float azf = (float)(az + p1.y + p2.y + p3.y) * swz;
      const float anf = (float)(an + p1.z + p2.z + p3.z) * swn;
      const float r = sigmoid_f(xr + arf);           // xr has bih_r + bhh_r
      const float z = sigmoid_f(xz + azf);           // xz has bih_z + bhh_z
      const float n = tanh_f(xn + r * (anf + bhn));
      h = (1.0f - z) * n + z * h;
      hp_out[j] = h;
      ((signed char*)h2[(t & 1) ^ 1])[j] = (signed char)__float2int_rn(h * 127.0f);
    }
    xp += G3;
    hp_out += H_;
    __syncthreads();
  }
  if (q == 0 && hlast) hlast[b * H_ + j] = h;
}

__global__ __launch_bounds__(1024)
void gru_enc(const float* __restrict__ xg, const uint4* __restrict__ wQv,
             const float* __restrict__ sw, const float* __restrict__ bhh,
             float* __restrict__ hout, float* __restrict__ hlast, int S) {
  __shared__ uint32_t h2[2][64];
  __shared__ int4 partv[4][H_];
  gru_block(blockIdx.x, xg, wQv, sw, bhh, nullptr, hout, hlast, S, h2, partv);
}

// ---- fused: decoder GRU (blocks 0-31) || hn quantization (blocks 32-543) ----
__global__ __launch_bounds__(1024)
void dec_and_hquant(const float* __restrict__ xg_d, const uint4* __restrict__ wQ_d,
                    const float* __restrict__ sw_d, const float* __restrict__ bhh_d,
                    const float* __restrict__ hend, float* __restrict__ doutb,
                    const float* __restrict__ hn, uint32_t* __restrict__ hnq,
                    float* __restrict__ sahn) {
  __shared__ uint32_t h2[2][64];
  __shared__ int4 partv[4][H_];
  if (blockIdx.x < 32)
    gru_block(blockIdx.x, xg_d, wQ_d, sw_d, bhh_d, hend, doutb,
              (float*)nullptr, T_, h2, partv);
  else
    quant16(blockIdx.x - 32, hn, hnq, sahn, 8192, 256, 64);
}

// ---- fused: WEt GEMM (blocks 0-511) || doutb quantization (512-767) ----
__global__ __launch_bounds__(256)
void wet_and_dquant(const uint32_t* __restrict__ hnq, const float* __restrict__ sahn,
                    const uint32_t* __restrict__ W1q, const float* __restrict__ sW1,
                    float* __restrict__ WEt,
                    const float* __restrict__ doutb, uint32_t* __restrict__ dq,
                    float* __restrict__ sad) {
  if (blockIdx.x < 512)
    gemm_body(hnq, sahn, W1q, sW1, nullptr, WEt,
              blockIdx.x & 127, blockIdx.x >> 7, 8192, 256, 64, true, false);
  else
    quant_body(blockIdx.x - 512, doutb, nullptr, nullptr, nullptr,
               dq, sad, 1024, 256, 64);
}

__global__ __launch_bounds__(256)
void wd_gemm(const uint32_t* __restrict__ dq, const float* __restrict__ sad,
             const uint32_t* __restrict__ W2q, const float* __restrict__ sW2,
             float* __restrict__ WDb) {
  gemm_body(dq, sad, W2q, sW2, nullptr, WDb,
            blockIdx.x & 15, blockIdx.x >> 4, 1024, 256, 64, false, false);
}

// ---- fused pointer layer + masked log-softmax + loss accumulation ----
__global__ __launch_bounds__(256)
void pointer_loss(const float* __restrict__ WEt, const float* __restrict__ WD,
                  const float* __restrict__ Vv,
                  const int* __restrict__ Xindex, const int* __restrict__ Yindex,
                  const int* __restrict__ lens, float* __restrict__ out) {
  const int t = blockIdx.x, b = blockIdx.y;
  const int l = threadIdx.x;
  __shared__ float wd_s[H_], vv_s[H_];
  __shared__ float rbuf[4], sbuf[4], vy_s;
  const int bt = b * T_ + t;
  wd_s[l] = WD[(long)bt * H_ + l];
  vv_s[l] = Vv[l] * 1.0507009873554805f;
  __syncthreads();
  const float* wet = WEt + (long)b * H_ * L_;
  const float alpha = 1.6732632423543772f;
  float acc = 0.0f;
#pragma unroll 4
  for (int hh = 0; hh < H_; ++hh) {
    const float xsum = wet[hh * L_ + l] + wd_s[hh];
    const float sneg = alpha * (__expf(xsum) - 1.0f);
    const float s = xsum > 0.0f ? xsum : sneg;
    acc = fmaf(s, vv_s[hh], acc);
  }
  float v;
  {
    const float sneg = alpha * (__expf(acc) - 1.0f);
    v = 1.0507009873554805f * (acc > 0.0f ? acc : sneg);
  }
  const int start = Xindex[bt];
  const int len = lens[b];
  const bool valid = (l >= start) && (l < len);
  const int y = Yindex[bt];
  if (l == y) vy_s = v;
  float m = valid ? v : -INFINITY;
  for (int off = 32; off > 0; off >>= 1) m = fmaxf(m, __shfl_xor(m, off, 64));
  const int wid = l >> 6, lane = l & 63;
  if (lane == 0) rbuf[wid] = m;
  __syncthreads();
  const float mx = fmaxf(fmaxf(rbuf[0], rbuf[1]), fmaxf(rbuf[2], rbuf[3]));
  float e = valid ? __expf(v - mx) : 0.0f;
  for (int off = 32; off > 0; off >>= 1) e += __shfl_xor(e, off, 64);
  if (lane == 0) sbuf[wid] = e;
  __syncthreads();
  if (l == 0) {
    const float sum = sbuf[0] + sbuf[1] + sbuf[2] + sbuf[3];
    atomicAdd(out, (mx + __logf(sum) - vy_s) * (1.0f / (B_ * T_)));
  }
}

extern "C" void kernel_launch(void* const* d_in, const int* in_sizes, int n_in,
                              void* d_out, int out_size, void* d_ws, size_t ws_size,
                              hipStream_t stream) {
  (void)in_sizes; (void)n_in; (void)out_size; (void)ws_size;
  const int*   Xin    = (const int*)d_in[0];
  const int*   Xindex = (const int*)d_in[1];
  const int*   Yindex = (const int*)d_in[2];
  const int*   lens   = (const int*)d_in[3];
  const float* emb    = (const float*)d_in[4];
  const float* Wih_e  = (const float*)d_in[5];
  const float* Whh_e  = (const float*)d_in[6];
  const float* bih_e  = (const float*)d_in[7];
  const float* bhh_e  = (const float*)d_in[8];
  const float* Wih_d  = (const float*)d_in[9];
  const float* Whh_d  = (const float*)d_in[10];
  const float* bih_d  = (const float*)d_in[11];
  const float* bhh_d  = (const float*)d_in[12];
  const float* W1     = (const float*)d_in[13];
  const float* W2     = (const float*)d_in[14];
  const float* Vv     = (const float*)d_in[15];

  char* p = (char*)d_ws;
  auto take = [&](size_t bytes) { void* q = (void*)p; p += (bytes + 255) & ~(size_t)255; return q; };
  uint32_t* wQ_e   = (uint32_t*)take((size_t)64 * G3 * 4);
  uint32_t* wQ_d   = (uint32_t*)take((size_t)64 * G3 * 4);
  float*    sw_e   = (float*)take((size_t)768 * 4);
  float*    sw_d   = (float*)take((size_t)768 * 4);
  uint32_t* WihQ_e = (uint32_t*)take((size_t)768 * 80 * 4);
  uint32_t* WihQ_d = (uint32_t*)take((size_t)768 * 80 * 4);
  float*    sWih_e = (float*)take((size_t)768 * 4);
  float*    sWih_d = (float*)take((size_t)768 * 4);
  uint32_t* W1q    = (uint32_t*)take((size_t)256 * 64 * 4);
  uint32_t* W2q    = (uint32_t*)take((size_t)256 * 64 * 4);
  float*    sW1    = (float*)take((size_t)256 * 4);
  float*    sW2    = (float*)take((size_t)256 * 4);
  float*    bsum_e = (float*)take((size_t)768 * 4);
  float*    bsum_d = (float*)take((size_t)768 * 4);
  float*    xg_e   = (float*)take((size_t)8192 * 768 * 4);   // reused as WEt later
  float*    xg_d   = (float*)take((size_t)1024 * 768 * 4);
  float*    hn     = (float*)take((size_t)8192 * 256 * 4);
  float*    hend   = (float*)take((size_t)8192 * 4);
  float*    doutb  = (float*)take((size_t)1024 * 256 * 4);
  float*    WDb    = (float*)take((size_t)1024 * 256 * 4);
  uint32_t* Aqe    = (uint32_t*)take((size_t)8192 * 80 * 4); // reused as hnq later
  float*    saAe   = (float*)take((size_t)8192 * 4);         // reused as sahn
  uint32_t* Aqd    = (uint32_t*)take((size_t)1024 * 80 * 4); // reused as dq
  float*    saAd   = (float*)take((size_t)1024 * 4);         // reused as sad
  float*    WEt  = xg_e;            // xg_e dead after encoder GRU
  uint32_t* hnq  = Aqe;             // Aqe dead after xg GEMMs
  float*    sahn = saAe;
  uint32_t* dq   = Aqd;
  float*    sad  = saAd;

  hipMemsetAsync(d_out, 0, sizeof(float), stream);

  // 1. fused prep: packs + weight quants + emb quants + bias sums
  hipLaunchKernelGGL(prep_all, dim3(3206), dim3(256), 0, stream,
                     Whh_e, Whh_d, wQ_e, wQ_d, sw_e, sw_d,
                     Wih_e, Wih_d, WihQ_e, WihQ_d, sWih_e, sWih_d,
                     W1, W2, W1q, W2q, sW1, sW2,
                     emb, Xin, Xindex, Aqe, saAe, Aqd, saAd,
                     bih_e, bhh_e, bsum_e, bih_d, bhh_d, bsum_d);

  // 2. fused xg GEMMs (encoder 1536 blocks + decoder 192 blocks)
  hipLaunchKernelGGL(xg_gemms, dim3(1728), dim3(256), 0, stream,
                     Aqe, saAe, WihQ_e, sWih_e, bsum_e, xg_e,
                     Aqd, saAd, WihQ_d, sWih_d, bsum_d, xg_d);

  // 3. encoder GRU -> hn, hend
  hipLaunchKernelGGL(gru_enc, dim3(32), dim3(1024), 0, stream,
                     xg_e, (const uint4*)wQ_e, sw_e, bhh_e, hn, hend, L_);

  // 4. decoder GRU || hn quantization
  hipLaunchKernelGGL(dec_and_hquant, dim3(544), dim3(1024), 0, stream,
                     xg_d, (const uint4*)wQ_d, sw_d, bhh_d, hend, doutb,
                     hn, hnq, sahn);

  // 5. WEt GEMM || doutb quantization
  hipLaunchKernelGGL(wet_and_dquant, dim3(768), dim3(256), 0, stream,
                     hnq, sahn, W1q, sW1, WEt, doutb, dq, sad);

  // 6. WD GEMM
  hipLaunchKernelGGL(wd_gemm, dim3(64), dim3(256), 0, stream,
                     dq, sad, W2q, sW2, WDb);

  // 7. fused pointer layer + loss
  hipLaunchKernelGGL(pointer_loss, dim3(T_, B_), dim3(256), 0, stream,
                     WEt, WDb, Vv, Xindex, Yindex, lens, (float*)d_out);
}

// Round 18
// 299.776 us; speedup vs baseline: 1.3149x; 1.0050x over previous
//
#include <hip/hip_runtime.h>
#include <hip/hip_bf16.h>
#include <stdint.h>

#define B_  32
#define L_  256
#define T_  32
#define D_  300
#define H_  256
#define G3  768   // 3*H

__device__ __forceinline__ int sdot4(uint32_t a, uint32_t b, int acc) {
#if defined(__has_builtin) && __has_builtin(__builtin_amdgcn_sdot4)
  return __builtin_amdgcn_sdot4((int)a, (int)b, acc, false);
#else
  const int a0 = (int)(signed char)(a & 0xff),  b0 = (int)(signed char)(b & 0xff);
  const int a1 = (int)(signed char)((a >> 8) & 0xff),  b1 = (int)(signed char)((b >> 8) & 0xff);
  const int a2 = (int)(signed char)((a >> 16) & 0xff), b2 = (int)(signed char)((b >> 16) & 0xff);
  const int a3 = (int)(signed char)(a >> 24),          b3 = (int)(signed char)(b >> 24);
  return acc + a0 * b0 + a1 * b1 + a2 * b2 + a3 * b3;
#endif
}

__device__ __forceinline__ float rcp_f(float x) { return __builtin_amdgcn_rcpf(x); }
__device__ __forceinline__ float sigmoid_f(float x) { return rcp_f(1.0f + __expf(-x)); }
__device__ __forceinline__ float tanh_f(float x) {
  float e2 = __expf(2.0f * x);
  return 1.0f - 2.0f * rcp_f(e2 + 1.0f);
}
__device__ __forceinline__ uint16_t f2bf(float x) {
  uint32_t u = __builtin_bit_cast(uint32_t, x);
  return (uint16_t)((u + 0x7FFF + ((u >> 16) & 1)) >> 16);
}
__device__ __forceinline__ float bf2f(uint16_t b) {
  uint32_t u = ((uint32_t)b) << 16;
  return __builtin_bit_cast(float, u);
}

// ---- pack Whh [768][256] f32 -> i4 nibble-packed uint4[8 chunks][768 rows] ----
// packed dword pd (0..31/row) holds k-dwords 2pd (low nibbles), 2pd+1 (high).
// unpack yields bytes = 16*value; sw = rowmax/(7*127*16) premultiplied.
__device__ __forceinline__ void pack_body(int blk, const float* __restrict__ Whh,
                                          uint32_t* __restrict__ wQ,
                                          float* __restrict__ sw) {
  const int row = blk * 4 + (threadIdx.x >> 6);
  const int lane = threadIdx.x & 63;
  const float* wr = Whh + (long)row * H_;
  float m = 0.0f;
#pragma unroll
  for (int u = 0; u < 4; ++u) m = fmaxf(m, fabsf(wr[lane + 64 * u]));
  for (int off = 32; off > 0; off >>= 1) m = fmaxf(m, __shfl_xor(m, off, 64));
  const float inv = m > 0.0f ? 7.0f / m : 0.0f;
  if (lane == 0) sw[row] = m > 0.0f ? m / (7.0f * 127.0f * 16.0f) : 0.0f;
  if (lane < 32) {
    const int pd = lane;
    uint32_t d = 0;
#pragma unroll
    for (int u = 0; u < 4; ++u) {
      int lo = __float2int_rn(wr[8 * pd + u] * inv);
      int hi = __float2int_rn(wr[8 * pd + 4 + u] * inv);
      lo = lo > 7 ? 7 : (lo < -7 ? -7 : lo);
      hi = hi > 7 ? 7 : (hi < -7 ? -7 : hi);
      d |= ((uint32_t)((lo & 0xF) | ((hi & 0xF) << 4))) << (8 * u);
    }
    wQ[(((size_t)(pd >> 2) * G3 + row) << 2) + (pd & 3)] = d;
  }
}

// ---- per-row symmetric i8 quantizer, 4 rows/block (256 threads) ----
__device__ __forceinline__ void quant_body(int blk, const float* __restrict__ A,
                                           const int* __restrict__ rowidx,
                                           const int* __restrict__ Xin2,
                                           const int* __restrict__ Xidx2,
                                           uint32_t* __restrict__ out,
                                           float* __restrict__ scale,
                                           int M, int K, int Kd) {
  const int row = blk * 4 + (threadIdx.x >> 6);
  const int lane = threadIdx.x & 63;
  if (row >= M) return;
  long src = row;
  if (rowidx) src = rowidx[row];
  else if (Xin2) src = Xin2[(row >> 5) * L_ + Xidx2[row]];
  const float* ar = A + src * (long)K;
  float m = 0.0f;
  for (int e = lane; e < K; e += 64) m = fmaxf(m, fabsf(ar[e]));
  for (int off = 32; off > 0; off >>= 1) m = fmaxf(m, __shfl_xor(m, off, 64));
  const float inv = m > 0.0f ? 127.0f / m : 0.0f;
  if (lane == 0) scale[row] = m * (1.0f / 127.0f);
  for (int kd = lane; kd < Kd; kd += 64) {
    uint32_t d = 0;
#pragma unroll
    for (int u = 0; u < 4; ++u) {
      const int e = 4 * kd + u;
      int qv = (e < K) ? __float2int_rn(ar[e] * inv) : 0;
      qv = qv > 127 ? 127 : (qv < -127 ? -127 : qv);
      d |= ((uint32_t)(qv & 0xff)) << (8 * u);
    }
    out[(long)row * Kd + kd] = d;
  }
}

// ---- 16 rows/block variant (1024 threads) ----
__device__ __forceinline__ void quant16(int blk, const float* __restrict__ A,
                                        uint32_t* __restrict__ out,
                                        float* __restrict__ scale,
                                        int M, int K, int Kd) {
  const int row = blk * 16 + (threadIdx.x >> 6);
  const int lane = threadIdx.x & 63;
  if (row >= M) return;
  const float* ar = A + (long)row * K;
  float m = 0.0f;
  for (int e = lane; e < K; e += 64) m = fmaxf(m, fabsf(ar[e]));
  for (int off = 32; off > 0; off >>= 1) m = fmaxf(m, __shfl_xor(m, off, 64));
  const float inv = m > 0.0f ? 127.0f / m : 0.0f;
  if (lane == 0) scale[row] = m * (1.0f / 127.0f);
  for (int kd = lane; kd < Kd; kd += 64) {
    uint32_t d = 0;
#pragma unroll
    for (int u = 0; u < 4; ++u) {
      const int e = 4 * kd + u;
      int qv = (e < K) ? __float2int_rn(ar[e] * inv) : 0;
      qv = qv > 127 ? 127 : (qv < -127 ? -127 : qv);
      d |= ((uint32_t)(qv & 0xff)) << (8 * u);
    }
    out[(long)row * Kd + kd] = d;
  }
}

// ---- one fused prep kernel: packs, weight/emb quants, bias sums ----
__global__ __launch_bounds__(256)
void prep_all(const float* __restrict__ Whh_e, const float* __restrict__ Whh_d,
              uint32_t* __restrict__ wQ_e, uint32_t* __restrict__ wQ_d,
              float* __restrict__ sw_e, float* __restrict__ sw_d,
              const float* __restrict__ Wih_e, const float* __restrict__ Wih_d,
              uint32_t* __restrict__ WihQ_e, uint32_t* __restrict__ WihQ_d,
              float* __restrict__ sWih_e, float* __restrict__ sWih_d,
              const float* __restrict__ W1, const float* __restrict__ W2,
              uint32_t* __restrict__ W1q, uint32_t* __restrict__ W2q,
              float* __restrict__ sW1, float* __restrict__ sW2,
              const float* __restrict__ emb, const int* __restrict__ Xin,
              const int* __restrict__ Xindex,
              uint32_t* __restrict__ Aqe, float* __restrict__ saAe,
              uint32_t* __restrict__ Aqd, float* __restrict__ saAd,
              const float* __restrict__ bih_e, const float* __restrict__ bhh_e,
              float* __restrict__ bsum_e,
              const float* __restrict__ bih_d, const float* __restrict__ bhh_d,
              float* __restrict__ bsum_d) {
  const int blk = blockIdx.x;
  if (blk < 192)        pack_body(blk, Whh_e, wQ_e, sw_e);
  else if (blk < 384)   pack_body(blk - 192, Whh_d, wQ_d, sw_d);
  else if (blk < 576)   quant_body(blk - 384, Wih_e, nullptr, nullptr, nullptr,
                                   WihQ_e, sWih_e, 768, 300, 80);
  else if (blk < 768)   quant_body(blk - 576, Wih_d, nullptr, nullptr, nullptr,
                                   WihQ_d, sWih_d, 768, 300, 80);
  else if (blk < 832)   quant_body(blk - 768, W1, nullptr, nullptr, nullptr,
                                   W1q, sW1, 256, 256, 64);
  else if (blk < 896)   quant_body(blk - 832, W2, nullptr, nullptr, nullptr,
                                   W2q, sW2, 256, 256, 64);
  else if (blk < 2944)  quant_body(blk - 896, emb, Xin, nullptr, nullptr,
                                   Aqe, saAe, 8192, 300, 80);
  else if (blk < 3200)  quant_body(blk - 2944, emb, nullptr, Xin, Xindex,
                                   Aqd, saAd, 1024, 300, 80);
  else {
    const int blk2 = blk - 3200;              // 0..5
    const int i = (blk2 % 3) * 256 + threadIdx.x;
    const float* bih = blk2 < 3 ? bih_e : bih_d;
    const float* bhh = blk2 < 3 ? bhh_e : bhh_d;
    float* bsum = blk2 < 3 ? bsum_e : bsum_d;
    float v = bih[i];
    if (i < 2 * H_) v += bhh[i];
    bsum[i] = v;
  }
}

// ---- i8 GEMM body; optional bf16 output ----
__device__ __forceinline__
void gemm_body(const uint32_t* __restrict__ Aq, const float* __restrict__ sa,
               const uint32_t* __restrict__ Wq, const float* __restrict__ swc,
               const float* __restrict__ bias, void* __restrict__ C,
               int bm, int bn, int M, int N, int Kd,
               bool transp, bool biasF, bool bf16out) {
  __shared__ uint32_t As[8][68];
  __shared__ uint32_t Ws[8][68];
  const int tid = threadIdx.x;
  const int ty = tid >> 4, tx = tid & 15;
  const int srow = tid >> 2;
  const int skd = (tid & 3) << 1;
  const uint32_t* Arow = Aq + (long)(bm * 64 + srow) * Kd + skd;
  const uint32_t* Wrow = Wq + (long)(bn * 64 + srow) * Kd + skd;
  int acc[4][4] = {};
  for (int k0 = 0; k0 < Kd; k0 += 8) {
    const uint32_t a0 = Arow[k0], a1 = Arow[k0 + 1];
    const uint32_t w0 = Wrow[k0], w1 = Wrow[k0 + 1];
    __syncthreads();
    As[skd][srow] = a0; As[skd + 1][srow] = a1;
    Ws[skd][srow] = w0; Ws[skd + 1][srow] = w1;
    __syncthreads();
#pragma unroll
    for (int kd = 0; kd < 8; ++kd) {
      const uint4 a4 = *(const uint4*)&As[kd][ty << 2];
      const uint4 b4 = *(const uint4*)&Ws[kd][tx << 2];
      acc[0][0] = sdot4(a4.x, b4.x, acc[0][0]);
      acc[0][1] = sdot4(a4.x, b4.y, acc[0][1]);
      acc[0][2] = sdot4(a4.x, b4.z, acc[0][2]);
      acc[0][3] = sdot4(a4.x, b4.w, acc[0][3]);
      acc[1][0] = sdot4(a4.y, b4.x, acc[1][0]);
      acc[1][1] = sdot4(a4.y, b4.y, acc[1][1]);
      acc[1][2] = sdot4(a4.y, b4.z, acc[1][2]);
      acc[1][3] = sdot4(a4.y, b4.w, acc[1][3]);
      acc[2][0] = sdot4(a4.z, b4.x, acc[2][0]);
      acc[2][1] = sdot4(a4.z, b4.y, acc[2][1]);
      acc[2][2] = sdot4(a4.z, b4.z, acc[2][2]);
      acc[2][3] = sdot4(a4.z, b4.w, acc[2][3]);
      acc[3][0] = sdot4(a4.w, b4.x, acc[3][0]);
      acc[3][1] = sdot4(a4.w, b4.y, acc[3][1]);
      acc[3][2] = sdot4(a4.w, b4.z, acc[3][2]);
      acc[3][3] = sdot4(a4.w, b4.w, acc[3][3]);
    }
  }
#pragma unroll
  for (int i = 0; i < 4; ++i) {
    const int m = bm * 64 + (ty << 2) + i;
    const float sai = sa[m];
#pragma unroll
    for (int j = 0; j < 4; ++j) {
      const int n = bn * 64 + (tx << 2) + j;
      float v = (float)acc[i][j] * sai * swc[n];
      if (biasF) v += bias[n];
      const long idx = transp ? ((((long)(m >> 8) * N + n) << 8) + (m & 255))
                              : ((long)m * N + n);
      if (bf16out) ((uint16_t*)C)[idx] = f2bf(v);
      else         ((float*)C)[idx] = v;
    }
  }
}

// ---- fused xg GEMMs (encoder + decoder inputs), bf16 out ----
__global__ __launch_bounds__(256)
void xg_gemms(const uint32_t* __restrict__ Aqe, const float* __restrict__ saAe,
              const uint32_t* __restrict__ WihQ_e, const float* __restrict__ sWih_e,
              const float* __restrict__ bsum_e, uint16_t* __restrict__ xg_e,
              const uint32_t* __restrict__ Aqd, const float* __restrict__ saAd,
              const uint32_t* __restrict__ WihQ_d, const float* __restrict__ sWih_d,
              const float* __restrict__ bsum_d, uint16_t* __restrict__ xg_d) {
  const int blk = blockIdx.x;
  if (blk < 1536)
    gemm_body(Aqe, saAe, WihQ_e, sWih_e, bsum_e, xg_e,
              blk % 128, blk / 128, 8192, 768, 80, false, true, true);
  else {
    const int k = blk - 1536;
    gemm_body(Aqd, saAd, WihQ_d, sWih_d, bsum_d, xg_d,
              k % 16, k / 16, 1024, 768, 80, false, true, true);
  }
}

// ==== streaming GRU, i4 weights: 1024 thr, 4-way K-split, 6 coalesced b128
// loads/thread/step (98 KB/CU/step, half of r17's L2-port-bound 196 KB).
// Unpack: (d<<4)&0xF0F0F0F0 -> 16*lo-nibbles, d&0xF0F0F0F0 -> 16*hi-nibbles;
// the 16x folds into sw. h i8 double-buffered in LDS; xg read as bf16. ====

#define M4 0xF0F0F0F0u
#define DOT2P(acc, pdw, hA, hB) { \
  acc = sdot4((pdw << 4) & M4, hA, acc); acc = sdot4(pdw & M4, hB, acc); }
#define DOTG4(acc, pw_, hpa, hpb) { \
  DOT2P(acc, pw_.x, hpa.x, hpa.y) DOT2P(acc, pw_.y, hpa.z, hpa.w) \
  DOT2P(acc, pw_.z, hpb.x, hpb.y) DOT2P(acc, pw_.w, hpb.z, hpb.w) }

__device__ __forceinline__
void gru_block(int b, const uint16_t* __restrict__ xg, const uint4* __restrict__ wQv,
               const float* __restrict__ sw, const float* __restrict__ bhh,
               const float* __restrict__ h0, float* __restrict__ hout,
               float* __restrict__ hlast, int S,
               uint32_t (*h2)[64], int4 (*partv)[H_]) {
  const int tid = threadIdx.x;
  const int j = tid & 255;
  const int q = tid >> 8;
  const int base = (q * 2) * G3 + j;     // chunks 2q, 2q+1; row j
  float bhn = 0.0f, h = 0.0f, swr = 0.0f, swz = 0.0f, swn = 0.0f;
  const uint16_t* xp = xg + (long)b * S * G3;
  float* hp_out = hout + (long)b * S * H_;
  if (q == 0) {
    bhn = bhh[2 * H_ + j];
    swr = sw[j]; swz = sw[H_ + j]; swn = sw[2 * H_ + j];
    h = h0 ? h0[b * H_ + j] : 0.0f;
    ((signed char*)h2[0])[j] = (signed char)__float2int_rn(h * 127.0f);
  }
  __syncthreads();
  for (int t = 0; t < S; ++t) {
    const uint4* hq = (const uint4*)h2[t & 1] + q * 4;
    const uint4 hp0 = hq[0], hp1 = hq[1], hp2 = hq[2], hp3 = hq[3];
    float xr = 0.0f, xz = 0.0f, xn = 0.0f;
    if (q == 0) {
      xr = bf2f(xp[j]); xz = bf2f(xp[H_ + j]); xn = bf2f(xp[2 * H_ + j]);
    }
    int ar = 0, az = 0, an = 0;
    {
      const uint4 p0 = wQv[base];
      const uint4 p1 = wQv[base + G3];
      DOTG4(ar, p0, hp0, hp1) DOTG4(ar, p1, hp2, hp3)
    }
    {
      const uint4 p0 = wQv[base + H_];
      const uint4 p1 = wQv[base + G3 + H_];
      DOTG4(az, p0, hp0, hp1) DOTG4(az, p1, hp2, hp3)
    }
    {
      const uint4 p0 = wQv[base + 2 * H_];
      const uint4 p1 = wQv[base + G3 + 2 * H_];
      DOTG4(an, p0, hp0, hp1) DOTG4(an, p1, hp2, hp3)
    }
    if (q) partv[q][j] = make_int4(ar, az, an, 0);
    __syncthreads();
    if (q == 0) {
      const int4 p1 = partv[1][j];
      const int4 p2 = partv[2][j];
      const int4 p3 = partv[3][j];
      const float arf = (float)(ar + p1.x + p2.x + p3.x) * swr;
      const float azf = (float)(az + p1.y + p2.y + p3.y) * swz;
      const float anf = (float)(an + p1.z + p2.z + p3.z) * swn;
      const float r = sigmoid_f(xr + arf);           // xr has bih_r + bhh_r
      const float z = sigmoid_f(xz + azf);           // xz has bih_z + bhh_z
      const float n = tanh_f(xn + r * (anf + bhn));
      h = (1.0f - z) * n + z * h;
      hp_out[j] = h;
      ((signed char*)h2[(t & 1) ^ 1])[j] = (signed char)__float2int_rn(h * 127.0f);
    }
    xp += G3;
    hp_out += H_;
    __syncthreads();
  }
  if (q == 0 && hlast) hlast[b * H_ + j] = h;
}

__global__ __launch_bounds__(1024)
void gru_enc(const uint16_t* __restrict__ xg, const uint4* __restrict__ wQv,
             const float* __restrict__ sw, const float* __restrict__ bhh,
             float* __restrict__ hout, float* __restrict__ hlast, int S) {
  __shared__ uint32_t h2[2][64];
  __shared__ int4 partv[4][H_];
  gru_block(blockIdx.x, xg, wQv, sw, bhh, nullptr, hout, hlast, S, h2, partv);
}

// ---- fused: decoder GRU (blocks 0-31) || hn quantization (blocks 32-543) ----
__global__ __launch_bounds__(1024)
void dec_and_hquant(const uint16_t* __restrict__ xg_d, const uint4* __restrict__ wQ_d,
                    const float* __restrict__ sw_d, const float* __restrict__ bhh_d,
                    const float* __restrict__ hend, float* __restrict__ doutb,
                    const float* __restrict__ hn, uint32_t* __restrict__ hnq,
                    float* __restrict__ sahn) {
  __shared__ uint32_t h2[2][64];
  __shared__ int4 partv[4][H_];
  if (blockIdx.x < 32)
    gru_block(blockIdx.x, xg_d, wQ_d, sw_d, bhh_d, hend, doutb,
              (float*)nullptr, T_, h2, partv);
  else
    quant16(blockIdx.x - 32, hn, hnq, sahn, 8192, 256, 64);
}

// ---- fused: WEt GEMM (blocks 0-511) || doutb quantization (512-767) ----
__global__ __launch_bounds__(256)
void wet_and_dquant(const uint32_t* __restrict__ hnq, const float* __restrict__ sahn,
                    const uint32_t* __restrict__ W1q, const float* __restrict__ sW1,
                    float* __restrict__ WEt,
                    const float* __restrict__ doutb, uint32_t* __restrict__ dq,
                    float* __restrict__ sad) {
  if (blockIdx.x < 512)
    gemm_body(hnq, sahn, W1q, sW1, nullptr, WEt,
              blockIdx.x & 127, blockIdx.x >> 7, 8192, 256, 64, true, false, false);
  else
    quant_body(blockIdx.x - 512, doutb, nullptr, nullptr, nullptr,
               dq, sad, 1024, 256, 64);
}

__global__ __launch_bounds__(256)
void wd_gemm(const uint32_t* __restrict__ dq, const float* __restrict__ sad,
             const uint32_t* __restrict__ W2q, const float* __restrict__ sW2,
             float* __restrict__ WDb) {
  gemm_body(dq, sad, W2q, sW2, nullptr, WDb,
            blockIdx.x & 15, blockIdx.x >> 4, 1024, 256, 64, false, false, false);
}

// ---- fused pointer layer + masked log-softmax + loss accumulation ----
__global__ __launch_bounds__(256)
void pointer_loss(const float* __restrict__ WEt, const float* __restrict__ WD,
                  const float* __restrict__ Vv,
                  const int* __restrict__ Xindex, const int* __restrict__ Yindex,
                  const int* __restrict__ lens, float* __restrict__ out) {
  const int t = blockIdx.x, b = blockIdx.y;
  const int l = threadIdx.x;
  __shared__ float wd_s[H_], vv_s[H_];
  __shared__ float rbuf[4], sbuf[4], vy_s;
  const int bt = b * T_ + t;
  wd_s[l] = WD[(long)bt * H_ + l];
  vv_s[l] = Vv[l] * 1.0507009873554805f;
  __syncthreads();
  const float* wet = WEt + (long)b * H_ * L_;
  const float alpha = 1.6732632423543772f;
  float acc = 0.0f;
#pragma unroll 4
  for (int hh = 0; hh < H_; ++hh) {
    const float xsum = wet[hh * L_ + l] + wd_s[hh];
    const float sneg = alpha * (__expf(xsum) - 1.0f);
    const float s = xsum > 0.0f ? xsum : sneg;
    acc = fmaf(s, vv_s[hh], acc);
  }
  float v;
  {
    const float sneg = alpha * (__expf(acc) - 1.0f);
    v = 1.0507009873554805f * (acc > 0.0f ? acc : sneg);
  }
  const int start = Xindex[bt];
  const int len = lens[b];
  const bool valid = (l >= start) && (l < len);
  const int y = Yindex[bt];
  if (l == y) vy_s = v;
  float m = valid ? v : -INFINITY;
  for (int off = 32; off > 0; off >>= 1) m = fmaxf(m, __shfl_xor(m, off, 64));
  const int wid = l >> 6, lane = l & 63;
  if (lane == 0) rbuf[wid] = m;
  __syncthreads();
  const float mx = fmaxf(fmaxf(rbuf[0], rbuf[1]), fmaxf(rbuf[2], rbuf[3]));
  float e = valid ? __expf(v - mx) : 0.0f;
  for (int off = 32; off > 0; off >>= 1) e += __shfl_xor(e, off, 64);
  if (lane == 0) sbuf[wid] = e;
  __syncthreads();
  if (l == 0) {
    const float sum = sbuf[0] + sbuf[1] + sbuf[2] + sbuf[3];
    atomicAdd(out, (mx + __logf(sum) - vy_s) * (1.0f / (B_ * T_)));
  }
}

extern "C" void kernel_launch(void* const* d_in, const int* in_sizes, int n_in,
                              void* d_out, int out_size, void* d_ws, size_t ws_size,
                              hipStream_t stream) {
  (void)in_sizes; (void)n_in; (void)out_size; (void)ws_size;
  const int*   Xin    = (const int*)d_in[0];
  const int*   Xindex = (const int*)d_in[1];
  const int*   Yindex = (const int*)d_in[2];
  const int*   lens   = (const int*)d_in[3];
  const float* emb    = (const float*)d_in[4];
  const float* Wih_e  = (const float*)d_in[5];
  const float* Whh_e  = (const float*)d_in[6];
  const float* bih_e  = (const float*)d_in[7];
  const float* bhh_e  = (const float*)d_in[8];
  const float* Wih_d  = (const float*)d_in[9];
  const float* Whh_d  = (const float*)d_in[10];
  const float* bih_d  = (const float*)d_in[11];
  const float* bhh_d  = (const float*)d_in[12];
  const float* W1     = (const float*)d_in[13];
  const float* W2     = (const float*)d_in[14];
  const float* Vv     = (const float*)d_in[15];

  char* p = (char*)d_ws;
  auto take = [&](size_t bytes) { void* q = (void*)p; p += (bytes + 255) & ~(size_t)255; return q; };
  uint32_t* wQ_e   = (uint32_t*)take((size_t)32 * G3 * 4);   // i4-packed
  uint32_t* wQ_d   = (uint32_t*)take((size_t)32 * G3 * 4);
  float*    sw_e   = (float*)take((size_t)768 * 4);
  float*    sw_d   = (float*)take((size_t)768 * 4);
  uint32_t* WihQ_e = (uint32_t*)take((size_t)768 * 80 * 4);
  uint32_t* WihQ_d = (uint32_t*)take((size_t)768 * 80 * 4);
  float*    sWih_e = (float*)take((size_t)768 * 4);
  float*    sWih_d = (float*)take((size_t)768 * 4);
  uint32_t* W1q    = (uint32_t*)take((size_t)256 * 64 * 4);
  uint32_t* W2q    = (uint32_t*)take((size_t)256 * 64 * 4);
  float*    sW1    = (float*)take((size_t)256 * 4);
  float*    sW2    = (float*)take((size_t)256 * 4);
  float*    bsum_e = (float*)take((size_t)768 * 4);
  float*    bsum_d = (float*)take((size_t)768 * 4);
  uint16_t* xg_e   = (uint16_t*)take((size_t)8192 * 768 * 2);  // bf16
  uint16_t* xg_d   = (uint16_t*)take((size_t)1024 * 768 * 2);
  float*    hn     = (float*)take((size_t)8192 * 256 * 4);
  float*    hend   = (float*)take((size_t)8192 * 4);
  float*    doutb  = (float*)take((size_t)1024 * 256 * 4);
  float*    WDb    = (float*)take((size_t)1024 * 256 * 4);
  float*    WEt    = (float*)take((size_t)8192 * 256 * 4);
  uint32_t* Aqe    = (uint32_t*)take((size_t)8192 * 80 * 4); // reused as hnq later
  float*    saAe   = (float*)take((size_t)8192 * 4);         // reused as sahn
  uint32_t* Aqd    = (uint32_t*)take((size_t)1024 * 80 * 4); // reused as dq
  float*    saAd   = (float*)take((size_t)1024 * 4);         // reused as sad
  uint32_t* hnq  = Aqe;             // Aqe dead after xg GEMMs
  float*    sahn = saAe;
  uint32_t* dq   = Aqd;
  float*    sad  = saAd;

  hipMemsetAsync(d_out, 0, sizeof(float), stream);

  // 1. fused prep: packs + weight quants + emb quants + bias sums
  hipLaunchKernelGGL(prep_all, dim3(3206), dim3(256), 0, stream,
                     Whh_e, Whh_d, wQ_e, wQ_d, sw_e, sw_d,
                     Wih_e, Wih_d, WihQ_e, WihQ_d, sWih_e, sWih_d,
                     W1, W2, W1q, W2q, sW1, sW2,
                     emb, Xin, Xindex, Aqe, saAe, Aqd, saAd,
                     bih_e, bhh_e, bsum_e, bih_d, bhh_d, bsum_d);

  // 2. fused xg GEMMs (bf16 out)
  hipLaunchKernelGGL(xg_gemms, dim3(1728), dim3(256), 0, stream,
                     Aqe, saAe, WihQ_e, sWih_e, bsum_e, xg_e,
                     Aqd, saAd, WihQ_d, sWih_d, bsum_d, xg_d);

  // 3. encoder GRU -> hn, hend
  hipLaunchKernelGGL(gru_enc, dim3(32), dim3(1024), 0, stream,
                     xg_e, (const uint4*)wQ_e, sw_e, bhh_e, hn, hend, L_);

  // 4. decoder GRU || hn quantization
  hipLaunchKernelGGL(dec_and_hquant, dim3(544), dim3(1024), 0, stream,
                     xg_d, (const uint4*)wQ_d, sw_d, bhh_d, hend, doutb,
                     hn, hnq, sahn);

  // 5. WEt GEMM || doutb quantization
  hipLaunchKernelGGL(wet_and_dquant, dim3(768), dim3(256), 0, stream,
                     hnq, sahn, W1q, sW1, WEt, doutb, dq, sad);

  // 6. WD GEMM
  hipLaunchKernelGGL(wd_gemm, dim3(64), dim3(256), 0, stream,
                     dq, sad, W2q, sW2, WDb);

  // 7. fused pointer layer + loss
  hipLaunchKernelGGL(pointer_loss, dim3(T_, B_), dim3(256), 0, stream,
                     WEt, WDb, Vv, Xindex, Yindex, lens, (float*)d_out);
}

// Round 19
// 285.709 us; speedup vs baseline: 1.3797x; 1.0492x over previous
//
#include <hip/hip_runtime.h>
#include <hip/hip_bf16.h>
#include <stdint.h>

#define B_  32
#define L_  256
#define T_  32
#define D_  300
#define H_  256
#define G3  768   // 3*H

__device__ __forceinline__ int sdot4(uint32_t a, uint32_t b, int acc) {
#if defined(__has_builtin) && __has_builtin(__builtin_amdgcn_sdot4)
  return __builtin_amdgcn_sdot4((int)a, (int)b, acc, false);
#else
  const int a0 = (int)(signed char)(a & 0xff),  b0 = (int)(signed char)(b & 0xff);
  const int a1 = (int)(signed char)((a >> 8) & 0xff),  b1 = (int)(signed char)((b >> 8) & 0xff);
  const int a2 = (int)(signed char)((a >> 16) & 0xff), b2 = (int)(signed char)((b >> 16) & 0xff);
  const int a3 = (int)(signed char)(a >> 24),          b3 = (int)(signed char)(b >> 24);
  return acc + a0 * b0 + a1 * b1 + a2 * b2 + a3 * b3;
#endif
}

// dot of 8 signed nibbles (nibble-major packing). Native v_dot8_i32_i4 when
// available; otherwise exact integer emulation (products*256, summed, >>8).
__device__ __forceinline__ int sdot8(uint32_t a, uint32_t b, int acc) {
#if defined(__has_builtin) && __has_builtin(__builtin_amdgcn_sdot8)
  return __builtin_amdgcn_sdot8((int)a, (int)b, acc, false);
#else
  const uint32_t M = 0xF0F0F0F0u;
  const uint32_t alo = (a << 4) & M, ahi = a & M;
  const uint32_t blo = (b << 4) & M, bhi = b & M;
  return acc + ((sdot4(alo, blo, 0) + sdot4(ahi, bhi, 0)) >> 8);
#endif
}

__device__ __forceinline__ float rcp_f(float x) { return __builtin_amdgcn_rcpf(x); }
__device__ __forceinline__ float sigmoid_f(float x) { return rcp_f(1.0f + __expf(-x)); }
__device__ __forceinline__ float tanh_f(float x) {
  float e2 = __expf(2.0f * x);
  return 1.0f - 2.0f * rcp_f(e2 + 1.0f);
}
__device__ __forceinline__ uint16_t f2bf(float x) {
  uint32_t u = __builtin_bit_cast(uint32_t, x);
  return (uint16_t)((u + 0x7FFF + ((u >> 16) & 1)) >> 16);
}
__device__ __forceinline__ float bf2f(uint16_t b) {
  uint32_t u = ((uint32_t)b) << 16;
  return __builtin_bit_cast(float, u);
}

// ---- pack Whh [768][256] f32 -> i4 nibble-MAJOR uint4[8 chunks][768 rows] ----
// packed dword pd (0..31/row): nibble jn = w[8pd+jn] (sdot8 operand layout).
// sw = rowmax/49 (weight scale rowmax/7 x h scale 1/7).
__device__ __forceinline__ void pack_body(int blk, const float* __restrict__ Whh,
                                          uint32_t* __restrict__ wQ,
                                          float* __restrict__ sw) {
  const int row = blk * 4 + (threadIdx.x >> 6);
  const int lane = threadIdx.x & 63;
  const float* wr = Whh + (long)row * H_;
  float m = 0.0f;
#pragma unroll
  for (int u = 0; u < 4; ++u) m = fmaxf(m, fabsf(wr[lane + 64 * u]));
  for (int off = 32; off > 0; off >>= 1) m = fmaxf(m, __shfl_xor(m, off, 64));
  const float inv = m > 0.0f ? 7.0f / m : 0.0f;
  if (lane == 0) sw[row] = m > 0.0f ? m / 49.0f : 0.0f;
  if (lane < 32) {
    const int pd = lane;
    uint32_t d = 0;
#pragma unroll
    for (int jn = 0; jn < 8; ++jn) {
      int v = __float2int_rn(wr[8 * pd + jn] * inv);
      v = v > 7 ? 7 : (v < -7 ? -7 : v);
      d |= ((uint32_t)(v & 0xF)) << (4 * jn);
    }
    wQ[(((size_t)(pd >> 2) * G3 + row) << 2) + (pd & 3)] = d;
  }
}

// ---- per-row symmetric i8 quantizer, 4 rows/block (256 threads) ----
__device__ __forceinline__ void quant_body(int blk, const float* __restrict__ A,
                                           const int* __restrict__ rowidx,
                                           const int* __restrict__ Xin2,
                                           const int* __restrict__ Xidx2,
                                           uint32_t* __restrict__ out,
                                           float* __restrict__ scale,
                                           int M, int K, int Kd) {
  const int row = blk * 4 + (threadIdx.x >> 6);
  const int lane = threadIdx.x & 63;
  if (row >= M) return;
  long src = row;
  if (rowidx) src = rowidx[row];
  else if (Xin2) src = Xin2[(row >> 5) * L_ + Xidx2[row]];
  const float* ar = A + src * (long)K;
  float m = 0.0f;
  for (int e = lane; e < K; e += 64) m = fmaxf(m, fabsf(ar[e]));
  for (int off = 32; off > 0; off >>= 1) m = fmaxf(m, __shfl_xor(m, off, 64));
  const float inv = m > 0.0f ? 127.0f / m : 0.0f;
  if (lane == 0) scale[row] = m * (1.0f / 127.0f);
  for (int kd = lane; kd < Kd; kd += 64) {
    uint32_t d = 0;
#pragma unroll
    for (int u = 0; u < 4; ++u) {
      const int e = 4 * kd + u;
      int qv = (e < K) ? __float2int_rn(ar[e] * inv) : 0;
      qv = qv > 127 ? 127 : (qv < -127 ? -127 : qv);
      d |= ((uint32_t)(qv & 0xff)) << (8 * u);
    }
    out[(long)row * Kd + kd] = d;
  }
}

// ---- 16 rows/block variant (1024 threads) ----
__device__ __forceinline__ void quant16(int blk, const float* __restrict__ A,
                                        uint32_t* __restrict__ out,
                                        float* __restrict__ scale,
                                        int M, int K, int Kd) {
  const int row = blk * 16 + (threadIdx.x >> 6);
  const int lane = threadIdx.x & 63;
  if (row >= M) return;
  const float* ar = A + (long)row * K;
  float m = 0.0f;
  for (int e = lane; e < K; e += 64) m = fmaxf(m, fabsf(ar[e]));
  for (int off = 32; off > 0; off >>= 1) m = fmaxf(m, __shfl_xor(m, off, 64));
  const float inv = m > 0.0f ? 127.0f / m : 0.0f;
  if (lane == 0) scale[row] = m * (1.0f / 127.0f);
  for (int kd = lane; kd < Kd; kd += 64) {
    uint32_t d = 0;
#pragma unroll
    for (int u = 0; u < 4; ++u) {
      const int e = 4 * kd + u;
      int qv = (e < K) ? __float2int_rn(ar[e] * inv) : 0;
      qv = qv > 127 ? 127 : (qv < -127 ? -127 : qv);
      d |= ((uint32_t)(qv & 0xff)) << (8 * u);
    }
    out[(long)row * Kd + kd] = d;
  }
}

// ---- one fused prep kernel: packs, weight/emb quants, bias sums ----
__global__ __launch_bounds__(256)
void prep_all(const float* __restrict__ Whh_e, const float* __restrict__ Whh_d,
              uint32_t* __restrict__ wQ_e, uint32_t* __restrict__ wQ_d,
              float* __restrict__ sw_e, float* __restrict__ sw_d,
              const float* __restrict__ Wih_e, const float* __restrict__ Wih_d,
              uint32_t* __restrict__ WihQ_e, uint32_t* __restrict__ WihQ_d,
              float* __restrict__ sWih_e, float* __restrict__ sWih_d,
              const float* __restrict__ W1, const float* __restrict__ W2,
              uint32_t* __restrict__ W1q, uint32_t* __restrict__ W2q,
              float* __restrict__ sW1, float* __restrict__ sW2,
              const float* __restrict__ emb, const int* __restrict__ Xin,
              const int* __restrict__ Xindex,
              uint32_t* __restrict__ Aqe, float* __restrict__ saAe,
              uint32_t* __restrict__ Aqd, float* __restrict__ saAd,
              const float* __restrict__ bih_e, const float* __restrict__ bhh_e,
              float* __restrict__ bsum_e,
              const float* __restrict__ bih_d, const float* __restrict__ bhh_d,
              float* __restrict__ bsum_d) {
  const int blk = blockIdx.x;
  if (blk < 192)        pack_body(blk, Whh_e, wQ_e, sw_e);
  else if (blk < 384)   pack_body(blk - 192, Whh_d, wQ_d, sw_d);
  else if (blk < 576)   quant_body(blk - 384, Wih_e, nullptr, nullptr, nullptr,
                                   WihQ_e, sWih_e, 768, 300, 80);
  else if (blk < 768)   quant_body(blk - 576, Wih_d, nullptr, nullptr, nullptr,
                                   WihQ_d, sWih_d, 768, 300, 80);
  else if (blk < 832)   quant_body(blk - 768, W1, nullptr, nullptr, nullptr,
                                   W1q, sW1, 256, 256, 64);
  else if (blk < 896)   quant_body(blk - 832, W2, nullptr, nullptr, nullptr,
                                   W2q, sW2, 256, 256, 64);
  else if (blk < 2944)  quant_body(blk - 896, emb, Xin, nullptr, nullptr,
                                   Aqe, saAe, 8192, 300, 80);
  else if (blk < 3200)  quant_body(blk - 2944, emb, nullptr, Xin, Xindex,
                                   Aqd, saAd, 1024, 300, 80);
  else {
    const int blk2 = blk - 3200;              // 0..5
    const int i = (blk2 % 3) * 256 + threadIdx.x;
    const float* bih = blk2 < 3 ? bih_e : bih_d;
    const float* bhh = blk2 < 3 ? bhh_e : bhh_d;
    float* bsum = blk2 < 3 ? bsum_e : bsum_d;
    float v = bih[i];
    if (i < 2 * H_) v += bhh[i];
    bsum[i] = v;
  }
}

// ---- i8 GEMM body; optional bf16 output ----
__device__ __forceinline__
void gemm_body(const uint32_t* __restrict__ Aq, const float* __restrict__ sa,
               const uint32_t* __restrict__ Wq, const float* __restrict__ swc,
               const float* __restrict__ bias, void* __restrict__ C,
               int bm, int bn, int M, int N, int Kd,
               bool transp, bool biasF, bool bf16out) {
  __shared__ uint32_t As[8][68];
  __shared__ uint32_t Ws[8][68];
  const int tid = threadIdx.x;
  const int ty = tid >> 4, tx = tid & 15;
  const int srow = tid >> 2;
  const int skd = (tid & 3) << 1;
  const uint32_t* Arow = Aq + (long)(bm * 64 + srow) * Kd + skd;
  const uint32_t* Wrow = Wq + (long)(bn * 64 + srow) * Kd + skd;
  int acc[4][4] = {};
  for (int k0 = 0; k0 < Kd; k0 += 8) {
    const uint32_t a0 = Arow[k0], a1 = Arow[k0 + 1];
    const uint32_t w0 = Wrow[k0], w1 = Wrow[k0 + 1];
    __syncthreads();
    As[skd][srow] = a0; As[skd + 1][srow] = a1;
    Ws[skd][srow] = w0; Ws[skd + 1][srow] = w1;
    __syncthreads();
#pragma unroll
    for (int kd = 0; kd < 8; ++kd) {
      const uint4 a4 = *(const uint4*)&As[kd][ty << 2];
      const uint4 b4 = *(const uint4*)&Ws[kd][tx << 2];
      acc[0][0] = sdot4(a4.x, b4.x, acc[0][0]);
      acc[0][1] = sdot4(a4.x, b4.y, acc[0][1]);
      acc[0][2] = sdot4(a4.x, b4.z, acc[0][2]);
      acc[0][3] = sdot4(a4.x, b4.w, acc[0][3]);
      acc[1][0] = sdot4(a4.y, b4.x, acc[1][0]);
      acc[1][1] = sdot4(a4.y, b4.y, acc[1][1]);
      acc[1][2] = sdot4(a4.y, b4.z, acc[1][2]);
      acc[1][3] = sdot4(a4.y, b4.w, acc[1][3]);
      acc[2][0] = sdot4(a4.z, b4.x, acc[2][0]);
      acc[2][1] = sdot4(a4.z, b4.y, acc[2][1]);
      acc[2][2] = sdot4(a4.z, b4.z, acc[2][2]);
      acc[2][3] = sdot4(a4.z, b4.w, acc[2][3]);
      acc[3][0] = sdot4(a4.w, b4.x, acc[3][0]);
      acc[3][1] = sdot4(a4.w, b4.y, acc[3][1]);
      acc[3][2] = sdot4(a4.w, b4.z, acc[3][2]);
      acc[3][3] = sdot4(a4.w, b4.w, acc[3][3]);
    }
  }
#pragma unroll
  for (int i = 0; i < 4; ++i) {
    const int m = bm * 64 + (ty << 2) + i;
    const float sai = sa[m];
#pragma unroll
    for (int j = 0; j < 4; ++j) {
      const int n = bn * 64 + (tx << 2) + j;
      float v = (float)acc[i][j] * sai * swc[n];
      if (biasF) v += bias[n];
      const long idx = transp ? ((((long)(m >> 8) * N + n) << 8) + (m & 255))
                              : ((long)m * N + n);
      if (bf16out) ((uint16_t*)C)[idx] = f2bf(v);
      else         ((float*)C)[idx] = v;
    }
  }
}

// ---- fused xg GEMMs (encoder + decoder inputs), bf16 out ----
__global__ __launch_bounds__(256)
void xg_gemms(const uint32_t* __restrict__ Aqe, const float* __restrict__ saAe,
              const uint32_t* __restrict__ WihQ_e, const float* __restrict__ sWih_e,
              const float* __restrict__ bsum_e, uint16_t* __restrict__ xg_e,
              const uint32_t* __restrict__ Aqd, const float* __restrict__ saAd,
              const uint32_t* __restrict__ WihQ_d, const float* __restrict__ sWih_d,
              const float* __restrict__ bsum_d, uint16_t* __restrict__ xg_d) {
  const int blk = blockIdx.x;
  if (blk < 1536)
    gemm_body(Aqe, saAe, WihQ_e, sWih_e, bsum_e, xg_e,
              blk % 128, blk / 128, 8192, 768, 80, false, true, true);
  else {
    const int k = blk - 1536;
    gemm_body(Aqd, saAd, WihQ_d, sWih_d, bsum_d, xg_d,
              k % 16, k / 16, 1024, 768, 80, false, true, true);
  }
}

// ==== streaming GRU, i4 weights x i4 h via sdot8: 1024 thr, 4-way K-split.
// Per thread/step: 6 coalesced b128 weight loads + 24 sdot8 + 2 LDS b128
// h-reads -- no nibble unpack (r18 was issue-bound: 72 unpack of 142 inst).
// h quantized to i4 (scale 7) for the matvec only; recurrence h stays f32.

#define DOT8V(acc, p_, h_) { \
  acc = sdot8(p_.x, h_.x, acc); acc = sdot8(p_.y, h_.y, acc); \
  acc = sdot8(p_.z, h_.z, acc); acc = sdot8(p_.w, h_.w, acc); }

__device__ __forceinline__
void gru_block(int b, const uint16_t* __restrict__ xg, const uint4* __restrict__ wQv,
               const float* __restrict__ sw, const float* __restrict__ bhh,
               const float* __restrict__ h0, float* __restrict__ hout,
               float* __restrict__ hlast, int S,
               uint32_t (*h2)[32], int4 (*partv)[H_]) {
  const int tid = threadIdx.x;
  const int j = tid & 255;
  const int q = tid >> 8;
  const int base = (q * 2) * G3 + j;     // chunks 2q, 2q+1; row j
  float bhn = 0.0f, h = 0.0f, swr = 0.0f, swz = 0.0f, swn = 0.0f;
  const uint16_t* xp = xg + (long)b * S * G3;
  float* hp_out = hout + (long)b * S * H_;
  if (q == 0) {
    bhn = bhh[2 * H_ + j];
    swr = sw[j]; swz = sw[H_ + j]; swn = sw[2 * H_ + j];
    h = h0 ? h0[b * H_ + j] : 0.0f;
    int hq4 = __float2int_rn(h * 7.0f);
    hq4 = hq4 > 7 ? 7 : (hq4 < -7 ? -7 : hq4);
    const int hq4n = __shfl_down(hq4, 1, 64);
    if (!(j & 1))
      ((uint8_t*)h2[0])[j >> 1] = (uint8_t)((hq4 & 0xF) | ((hq4n & 0xF) << 4));
  }
  __syncthreads();
  for (int t = 0; t < S; ++t) {
    const uint4* hq = (const uint4*)h2[t & 1] + q * 2;
    const uint4 ha = hq[0], hb = hq[1];
    float xr = 0.0f, xz = 0.0f, xn = 0.0f;
    if (q == 0) {
      xr = bf2f(xp[j]); xz = bf2f(xp[H_ + j]); xn = bf2f(xp[2 * H_ + j]);
    }
    int ar = 0, az = 0, an = 0;
    {
      const uint4 p0 = wQv[base], p1 = wQv[base + G3];
      DOT8V(ar, p0, ha) DOT8V(ar, p1, hb)
    }
    {
      const uint4 p0 = wQv[base + H_], p1 = wQv[base + G3 + H_];
      DOT8V(az, p0, ha) DOT8V(az, p1, hb)
    }
    {
      const uint4 p0 = wQv[base + 2 * H_], p1 = wQv[base + G3 + 2 * H_];
      DOT8V(an, p0, ha) DOT8V(an, p1, hb)
    }
    if (q) partv[q][j] = make_int4(ar, az, an, 0);
    __syncthreads();
    if (q == 0) {
      const int4 p1 = partv[1][j];
      const int4 p2 = partv[2][j];
      const int4 p3 = partv[3][j];
      const float arf = (float)(ar + p1.x + p2.x + p3.x) * swr;
      const float azf = (float)(az + p1.y + p2.y + p3.y) * swz;
      const float anf = (float)(an + p1.z + p2.z + p3.z) * swn;
      const float r = sigmoid_f(xr + arf);           // xr has bih_r + bhh_r
      const float z = sigmoid_f(xz + azf);           // xz has bih_z + bhh_z
      const float n = tanh_f(xn + r * (anf + bhn));
      h = (1.0f - z) * n + z * h;
      hp_out[j] = h;
      int hq4 = __float2int_rn(h * 7.0f);
      hq4 = hq4 > 7 ? 7 : (hq4 < -7 ? -7 : hq4);
      const int hq4n = __shfl_down(hq4, 1, 64);
      if (!(j & 1))
        ((uint8_t*)h2[(t & 1) ^ 1])[j >> 1] =
            (uint8_t)((hq4 & 0xF) | ((hq4n & 0xF) << 4));
    }
    xp += G3;
    hp_out += H_;
    __syncthreads();
  }
  if (q == 0 && hlast) hlast[b * H_ + j] = h;
}

__global__ __launch_bounds__(1024)
void gru_enc(const uint16_t* __restrict__ xg, const uint4* __restrict__ wQv,
             const float* __restrict__ sw, const float* __restrict__ bhh,
             float* __restrict__ hout, float* __restrict__ hlast, int S) {
  __shared__ __align__(16) uint32_t h2[2][32];
  __shared__ int4 partv[4][H_];
  gru_block(blockIdx.x, xg, wQv, sw, bhh, nullptr, hout, hlast, S, h2, partv);
}

// ---- fused: decoder GRU (blocks 0-31) || hn quantization (blocks 32-543) ----
__global__ __launch_bounds__(1024)
void dec_and_hquant(const uint16_t* __restrict__ xg_d, const uint4* __restrict__ wQ_d,
                    const float* __restrict__ sw_d, const float* __restrict__ bhh_d,
                    const float* __restrict__ hend, float* __restrict__ doutb,
                    const float* __restrict__ hn, uint32_t* __restrict__ hnq,
                    float* __restrict__ sahn) {
  __shared__ __align__(16) uint32_t h2[2][32];
  __shared__ int4 partv[4][H_];
  if (blockIdx.x < 32)
    gru_block(blockIdx.x, xg_d, wQ_d, sw_d, bhh_d, hend, doutb,
              (float*)nullptr, T_, h2, partv);
  else
    quant16(blockIdx.x - 32, hn, hnq, sahn, 8192, 256, 64);
}

// ---- fused: WEt GEMM (blocks 0-511) || doutb quantization (512-767) ----
__global__ __launch_bounds__(256)
void wet_and_dquant(const uint32_t* __restrict__ hnq, const float* __restrict__ sahn,
                    const uint32_t* __restrict__ W1q, const float* __restrict__ sW1,
                    float* __restrict__ WEt,
                    const float* __restrict__ doutb, uint32_t* __restrict__ dq,
                    float* __restrict__ sad) {
  if (blockIdx.x < 512)
    gemm_body(hnq, sahn, W1q, sW1, nullptr, WEt,
              blockIdx.x & 127, blockIdx.x >> 7, 8192, 256, 64, true, false, false);
  else
    quant_body(blockIdx.x - 512, doutb, nullptr, nullptr, nullptr,
               dq, sad, 1024, 256, 64);
}

__global__ __launch_bounds__(256)
void wd_gemm(const uint32_t* __restrict__ dq, const float* __restrict__ sad,
             const uint32_t* __restrict__ W2q, const float* __restrict__ sW2,
             float* __restrict__ WDb) {
  gemm_body(dq, sad, W2q, sW2, nullptr, WDb,
            blockIdx.x & 15, blockIdx.x >> 4, 1024, 256, 64, false, false, false);
}

// ---- fused pointer layer + masked log-softmax + loss accumulation ----
__global__ __launch_bounds__(256)
void pointer_loss(const float* __restrict__ WEt, const float* __restrict__ WD,
                  const float* __restrict__ Vv,
                  const int* __restrict__ Xindex, const int* __restrict__ Yindex,
                  const int* __restrict__ lens, float* __restrict__ out) {
  const int t = blockIdx.x, b = blockIdx.y;
  const int l = threadIdx.x;
  __shared__ float wd_s[H_], vv_s[H_];
  __shared__ float rbuf[4], sbuf[4], vy_s;
  const int bt = b * T_ + t;
  wd_s[l] = WD[(long)bt * H_ + l];
  vv_s[l] = Vv[l] * 1.0507009873554805f;
  __syncthreads();
  const float* wet = WEt + (long)b * H_ * L_;
  const float alpha = 1.6732632423543772f;
  float acc = 0.0f;
#pragma unroll 4
  for (int hh = 0; hh < H_; ++hh) {
    const float xsum = wet[hh * L_ + l] + wd_s[hh];
    const float sneg = alpha * (__expf(xsum) - 1.0f);
    const float s = xsum > 0.0f ? xsum : sneg;
    acc = fmaf(s, vv_s[hh], acc);
  }
  float v;
  {
    const float sneg = alpha * (__expf(acc) - 1.0f);
    v = 1.0507009873554805f * (acc > 0.0f ? acc : sneg);
  }
  const int start = Xindex[bt];
  const int len = lens[b];
  const bool valid = (l >= start) && (l < len);
  const int y = Yindex[bt];
  if (l == y) vy_s = v;
  float m = valid ? v : -INFINITY;
  for (int off = 32; off > 0; off >>= 1) m = fmaxf(m, __shfl_xor(m, off, 64));
  const int wid = l >> 6, lane = l & 63;
  if (lane == 0) rbuf[wid] = m;
  __syncthreads();
  const float mx = fmaxf(fmaxf(rbuf[0], rbuf[1]), fmaxf(rbuf[2], rbuf[3]));
  float e = valid ? __expf(v - mx) : 0.0f;
  for (int off = 32; off > 0; off >>= 1) e += __shfl_xor(e, off, 64);
  if (lane == 0) sbuf[wid] = e;
  __syncthreads();
  if (l == 0) {
    const float sum = sbuf[0] + sbuf[1] + sbuf[2] + sbuf[3];
    atomicAdd(out, (mx + __logf(sum) - vy_s) * (1.0f / (B_ * T_)));
  }
}

extern "C" void kernel_launch(void* const* d_in, const int* in_sizes, int n_in,
                              void* d_out, int out_size, void* d_ws, size_t ws_size,
                              hipStream_t stream) {
  (void)in_sizes; (void)n_in; (void)out_size; (void)ws_size;
  const int*   Xin    = (const int*)d_in[0];
  const int*   Xindex = (const int*)d_in[1];
  const int*   Yindex = (const int*)d_in[2];
  const int*   lens   = (const int*)d_in[3];
  const float* emb    = (const float*)d_in[4];
  const float* Wih_e  = (const float*)d_in[5];
  const float* Whh_e  = (const float*)d_in[6];
  const float* bih_e  = (const float*)d_in[7];
  const float* bhh_e  = (const float*)d_in[8];
  const float* Wih_d  = (const float*)d_in[9];
  const float* Whh_d  = (const float*)d_in[10];
  const float* bih_d  = (const float*)d_in[11];
  const float* bhh_d  = (const float*)d_in[12];
  const float* W1     = (const float*)d_in[13];
  const float* W2     = (const float*)d_in[14];
  const float* Vv     = (const float*)d_in[15];

  char* p = (char*)d_ws;
  auto take = [&](size_t bytes) { void* q = (void*)p; p += (bytes + 255) & ~(size_t)255; return q; };
  uint32_t* wQ_e   = (uint32_t*)take((size_t)32 * G3 * 4);   // i4-packed
  uint32_t* wQ_d   = (uint32_t*)take((size_t)32 * G3 * 4);
  float*    sw_e   = (float*)take((size_t)768 * 4);
  float*    sw_d   = (float*)take((size_t)768 * 4);
  uint32_t* WihQ_e = (uint32_t*)take((size_t)768 * 80 * 4);
  uint32_t* WihQ_d = (uint32_t*)take((size_t)768 * 80 * 4);
  float*    sWih_e = (float*)take((size_t)768 * 4);
  float*    sWih_d = (float*)take((size_t)768 * 4);
  uint32_t* W1q    = (uint32_t*)take((size_t)256 * 64 * 4);
  uint32_t* W2q    = (uint32_t*)take((size_t)256 * 64 * 4);
  float*    sW1    = (float*)take((size_t)256 * 4);
  float*    sW2    = (float*)take((size_t)256 * 4);
  float*    bsum_e = (float*)take((size_t)768 * 4);
  float*    bsum_d = (float*)take((size_t)768 * 4);
  uint16_t* xg_e   = (uint16_t*)take((size_t)8192 * 768 * 2);  // bf16
  uint16_t* xg_d   = (uint16_t*)take((size_t)1024 * 768 * 2);
  float*    hn     = (float*)take((size_t)8192 * 256 * 4);
  float*    hend   = (float*)take((size_t)8192 * 4);
  float*    doutb  = (float*)take((size_t)1024 * 256 * 4);
  float*    WDb    = (float*)take((size_t)1024 * 256 * 4);
  float*    WEt    = (float*)take((size_t)8192 * 256 * 4);
  uint32_t* Aqe    = (uint32_t*)take((size_t)8192 * 80 * 4); // reused as hnq later
  float*    saAe   = (float*)take((size_t)8192 * 4);         // reused as sahn
  uint32_t* Aqd    = (uint32_t*)take((size_t)1024 * 80 * 4); // reused as dq
  float*    saAd   = (float*)take((size_t)1024 * 4);         // reused as sad
  uint32_t* hnq  = Aqe;             // Aqe dead after xg GEMMs
  float*    sahn = saAe;
  uint32_t* dq   = Aqd;
  float*    sad  = saAd;

  hipMemsetAsync(d_out, 0, sizeof(float), stream);

  // 1. fused prep: packs + weight quants + emb quants + bias sums
  hipLaunchKernelGGL(prep_all, dim3(3206), dim3(256), 0, stream,
                     Whh_e, Whh_d, wQ_e, wQ_d, sw_e, sw_d,
                     Wih_e, Wih_d, WihQ_e, WihQ_d, sWih_e, sWih_d,
                     W1, W2, W1q, W2q, sW1, sW2,
                     emb, Xin, Xindex, Aqe, saAe, Aqd, saAd,
                     bih_e, bhh_e, bsum_e, bih_d, bhh_d, bsum_d);

  // 2. fused xg GEMMs (bf16 out)
  hipLaunchKernelGGL(xg_gemms, dim3(1728), dim3(256), 0, stream,
                     Aqe, saAe, WihQ_e, sWih_e, bsum_e, xg_e,
                     Aqd, saAd, WihQ_d, sWih_d, bsum_d, xg_d);

  // 3. encoder GRU -> hn, hend
  hipLaunchKernelGGL(gru_enc, dim3(32), dim3(1024), 0, stream,
                     xg_e, (const uint4*)wQ_e, sw_e, bhh_e, hn, hend, L_);

  // 4. decoder GRU || hn quantization
  hipLaunchKernelGGL(dec_and_hquant, dim3(544), dim3(1024), 0, stream,
                     xg_d, (const uint4*)wQ_d, sw_d, bhh_d, hend, doutb,
                     hn, hnq, sahn);

  // 5. WEt GEMM || doutb quantization
  hipLaunchKernelGGL(wet_and_dquant, dim3(768), dim3(256), 0, stream,
                     hnq, sahn, W1q, sW1, WEt, doutb, dq, sad);

  // 6. WD GEMM
  hipLaunchKernelGGL(wd_gemm, dim3(64), dim3(256), 0, stream,
                     dq, sad, W2q, sW2, WDb);

  // 7. fused pointer layer + loss
  hipLaunchKernelGGL(pointer_loss, dim3(T_, B_), dim3(256), 0, stream,
                     WEt, WDb, Vv, Xindex, Yindex, lens, (float*)d_out);
}